// Round 2
// baseline (1551.894 us; speedup 1.0000x reference)
//
#include <hip/hip_runtime.h>
#include <hip/hip_cooperative_groups.h>

namespace cg = cooperative_groups;

// ---------------------------------------------------------------------------
// SlotAttention, single cooperative mega-kernel. bf16 MFMA GEMMs, fp32 rest.
// Fragment layouts per learn_hip m89/m97 (ref-verified):
//   A/B operand: idx = lane&15, k = (lane>>4)*8 + j   (8 contiguous bf16)
//   C/D:         col = lane&15, row = (lane>>4)*4 + reg
// ---------------------------------------------------------------------------

typedef __attribute__((ext_vector_type(8))) __bf16 bf16x8;
typedef __attribute__((ext_vector_type(4))) float  f32x4;

static __device__ __forceinline__ unsigned short f2bf(float f) {
    unsigned int x = __float_as_uint(f);
    x = (x + 0x7fffu + ((x >> 16) & 1u)) >> 16;   // RN-even
    return (unsigned short)x;
}
static __device__ __forceinline__ float bflo(unsigned int u) { return __uint_as_float(u << 16); }
static __device__ __forceinline__ float bfhi(unsigned int u) { return __uint_as_float(u & 0xffff0000u); }

// ------------- 128x128 bf16 MFMA tile: C_bf16[M,N] = A[M,K] @ B[N,K]^T -------
static __device__ void gemm128_kv(const unsigned short* __restrict__ A,
                                  const unsigned short* __restrict__ B,
                                  unsigned short* __restrict__ Cbf,
                                  int m0, int n0, int N, int K, int t, char* smem)
{
    unsigned short* As = (unsigned short*)smem;        // 128*32
    unsigned short* Bs = As + 128 * 32;                // 128*32
    const int wave = t >> 6, lane = t & 63;
    const int qr = (wave >> 1) * 64, qc = (wave & 1) * 64;
    const int lr = lane & 15, lq = lane >> 4;
    f32x4 acc[4][4] = {};
    const int sr = t >> 2, sc = (t & 3) * 8;
    for (int k0 = 0; k0 < K; k0 += 32) {
        __syncthreads();
        uint4 a0 = *(const uint4*)(A + (size_t)(m0 + sr) * K + k0 + sc);
        uint4 a1 = *(const uint4*)(A + (size_t)(m0 + sr + 64) * K + k0 + sc);
        uint4 b0 = *(const uint4*)(B + (size_t)(n0 + sr) * K + k0 + sc);
        uint4 b1 = *(const uint4*)(B + (size_t)(n0 + sr + 64) * K + k0 + sc);
        *(uint4*)(As + sr * 32 + sc) = a0;
        *(uint4*)(As + (sr + 64) * 32 + sc) = a1;
        *(uint4*)(Bs + sr * 32 + sc) = b0;
        *(uint4*)(Bs + (sr + 64) * 32 + sc) = b1;
        __syncthreads();
        bf16x8 af[4], bv[4];
        #pragma unroll
        for (int i = 0; i < 4; i++) af[i] = *(const bf16x8*)(As + (qr + i * 16 + lr) * 32 + lq * 8);
        #pragma unroll
        for (int i = 0; i < 4; i++) bv[i] = *(const bf16x8*)(Bs + (qc + i * 16 + lr) * 32 + lq * 8);
        #pragma unroll
        for (int i = 0; i < 4; i++)
            #pragma unroll
            for (int j = 0; j < 4; j++)
                acc[i][j] = __builtin_amdgcn_mfma_f32_16x16x32_bf16(af[i], bv[j], acc[i][j], 0, 0, 0);
    }
    #pragma unroll
    for (int i = 0; i < 4; i++)
        #pragma unroll
        for (int j = 0; j < 4; j++) {
            int col = n0 + qc + j * 16 + lr;
            #pragma unroll
            for (int r = 0; r < 4; r++) {
                int row = m0 + qr + i * 16 + lq * 4 + r;
                Cbf[(size_t)row * N + col] = f2bf(acc[i][j][r]);
            }
        }
}

// ------------- 64x64 bf16 MFMA tile, epilogue variants ----------------------
// EPI 1: C = acc + bias (fp32)
// EPI 2: Cbf = bf16(relu(acc + bias))
// EPI 3: r = acc + bias + res[idx]; res[idx] = r; if (fin) fout[idx] = r
template<int EPI>
static __device__ void gemm64_tile(const unsigned short* __restrict__ A,
                                   const unsigned short* __restrict__ B,
                                   float* __restrict__ C, unsigned short* __restrict__ Cbf,
                                   const float* __restrict__ bias,
                                   float* __restrict__ res, float* __restrict__ fout, int fin,
                                   int m0, int n0, int N, int K, int t, char* smem)
{
    unsigned short* As = (unsigned short*)smem;   // 64*32
    unsigned short* Bs = As + 64 * 32;
    const int wave = t >> 6, lane = t & 63;
    const int lr = lane & 15, lq = lane >> 4;
    f32x4 acc[4] = {};
    const int sr = t >> 2, sc = (t & 3) * 8;
    for (int k0 = 0; k0 < K; k0 += 32) {
        __syncthreads();
        uint4 a0 = *(const uint4*)(A + (size_t)(m0 + sr) * K + k0 + sc);
        uint4 b0 = *(const uint4*)(B + (size_t)(n0 + sr) * K + k0 + sc);
        *(uint4*)(As + sr * 32 + sc) = a0;
        *(uint4*)(Bs + sr * 32 + sc) = b0;
        __syncthreads();
        bf16x8 af = *(const bf16x8*)(As + (wave * 16 + lr) * 32 + lq * 8);
        #pragma unroll
        for (int j = 0; j < 4; j++) {
            bf16x8 bv = *(const bf16x8*)(Bs + (j * 16 + lr) * 32 + lq * 8);
            acc[j] = __builtin_amdgcn_mfma_f32_16x16x32_bf16(af, bv, acc[j], 0, 0, 0);
        }
    }
    #pragma unroll
    for (int j = 0; j < 4; j++) {
        int col = n0 + j * 16 + lr;
        #pragma unroll
        for (int r = 0; r < 4; r++) {
            int row = m0 + wave * 16 + lq * 4 + r;
            size_t idx = (size_t)row * N + col;
            float v = acc[j][r];
            if      (EPI == 1) C[idx] = v + bias[col];
            else if (EPI == 2) Cbf[idx] = f2bf(fmaxf(v + bias[col], 0.f));
            else {
                float rr = v + bias[col] + res[idx];
                res[idx] = rr;
                if (fin) fout[idx] = rr;
            }
        }
    }
}

// ---------------------------------------------------------------------------
__global__ __launch_bounds__(256, 2) void mega_kernel(
    const float* __restrict__ inputs, const float* __restrict__ noise,
    const float* __restrict__ mu,     const float* __restrict__ ls,
    const float* __restrict__ Wq,     const float* __restrict__ Wk,
    const float* __restrict__ Wv,     const float* __restrict__ wih,
    const float* __restrict__ whh,    const float* __restrict__ bih,
    const float* __restrict__ bhh,    const float* __restrict__ w1,
    const float* __restrict__ b1,     const float* __restrict__ w2,
    const float* __restrict__ b2,     const float* __restrict__ g_in,
    const float* __restrict__ b_in,   const float* __restrict__ g_s,
    const float* __restrict__ b_s,    const float* __restrict__ g_ff,
    const float* __restrict__ b_ff,   float* __restrict__ out,
    char* __restrict__ ws)
{
    __shared__ __align__(16) char smem[16896];
    cg::grid_group grid = cg::this_grid();
    const int t = threadIdx.x, bid = blockIdx.x, nB = gridDim.x;

    // workspace layout (bytes)
    unsigned short* x_bf   = (unsigned short*)(ws + 0);          // 32768x256 bf16
    unsigned short* kv_bf  = (unsigned short*)(ws + 16777216);   // 32768x512 bf16
    unsigned short* kvW_bf = (unsigned short*)(ws + 50331648);   // 512x256
    unsigned short* Wq_bf  = (unsigned short*)(ws + 50593792);   // 256x256
    unsigned short* wih_bf = (unsigned short*)(ws + 50724864);   // 768x256
    unsigned short* whh_bf = (unsigned short*)(ws + 51118080);   // 768x256
    unsigned short* w1_bf  = (unsigned short*)(ws + 51511296);   // 1024x256
    unsigned short* w2_bf  = (unsigned short*)(ws + 52035584);   // 256x1024
    float*          slots  = (float*)(ws + 52559872);            // 256x256 f32
    float*          qbuf   = (float*)(ws + 52822016);            // 256x256 f32
    float*          upart  = (float*)(ws + 53084160);            // 32x16x8x256 f32
    float*          rspart = (float*)(ws + 57278464);            // 32x16x8 f32
    unsigned short* u_bf   = (unsigned short*)(ws + 57294848);   // 256x256
    unsigned short* h_bf   = (unsigned short*)(ws + 57425920);   // 256x256
    float*          gi     = (float*)(ws + 57556992);            // 256x768 f32
    float*          gh     = (float*)(ws + 58343424);            // 256x768 f32
    unsigned short* ff_bf  = (unsigned short*)(ws + 59129856);   // 256x256
    unsigned short* h1_bf  = (unsigned short*)(ws + 59260928);   // 256x1024

    // ---------------- P0a: LN(inputs) -> x_bf (one wave per row) ------------
    {
        const int lane = t & 63;
        float4 g4 = *(const float4*)(g_in + lane * 4);
        float4 bb4 = *(const float4*)(b_in + lane * 4);
        for (int grp = bid; grp < 8192; grp += nB) {
            int row = grp * 4 + (t >> 6);
            float4 v = *(const float4*)(inputs + (size_t)row * 256 + lane * 4);
            float s = v.x + v.y + v.z + v.w;
            float ss = v.x * v.x + v.y * v.y + v.z * v.z + v.w * v.w;
            #pragma unroll
            for (int o = 32; o > 0; o >>= 1) { s += __shfl_xor(s, o); ss += __shfl_xor(ss, o); }
            float mean = s * (1.f / 256.f);
            float var  = ss * (1.f / 256.f) - mean * mean;
            float rstd = rsqrtf(var + 1e-5f);
            ushort4 o4;
            o4.x = f2bf((v.x - mean) * rstd * g4.x + bb4.x);
            o4.y = f2bf((v.y - mean) * rstd * g4.y + bb4.y);
            o4.z = f2bf((v.z - mean) * rstd * g4.z + bb4.z);
            o4.w = f2bf((v.w - mean) * rstd * g4.w + bb4.w);
            *(ushort4*)(x_bf + (size_t)row * 256 + lane * 4) = o4;
        }
    }
    // ---------------- P0b: weights -> bf16, slots init ----------------------
    for (int g = bid * 256 + t; g < 1179648; g += nB * 256) {
        if      (g <   65536) kvW_bf[g]          = f2bf(Wk[g]);
        else if (g <  131072) kvW_bf[g]          = f2bf(Wv[g -   65536]);
        else if (g <  196608) Wq_bf[g - 131072]  = f2bf(Wq[g -  131072]);
        else if (g <  393216) wih_bf[g - 196608] = f2bf(wih[g - 196608]);
        else if (g <  589824) whh_bf[g - 393216] = f2bf(whh[g - 393216]);
        else if (g <  851968) w1_bf[g - 589824]  = f2bf(w1[g -  589824]);
        else if (g < 1114112) w2_bf[g - 851968]  = f2bf(w2[g -  851968]);
        else {
            int i = g - 1114112, d = i & 255;
            slots[i] = mu[d] + __expf(ls[d]) * noise[i];
        }
    }
    grid.sync();

    // ---------------- P1: kv = x_ln @ [Wk;Wv]^T  (bf16 out) -----------------
    for (int w = bid; w < 1024; w += nB) {
        int mt = w >> 2, nt = w & 3;
        gemm128_kv(x_bf, kvW_bf, kv_bf, mt * 128, nt * 128, 512, 256, t, smem);
    }
    grid.sync();

    for (int it = 0; it < 3; ++it) {
        // -------- P2: LN_s + q = LN(slots) @ Wq^T (fp32) --------------------
        for (int row = bid; row < 256; row += nB) {
            float* lnr = (float*)smem;            // 256 floats
            float* red = (float*)(smem + 1024);   // 8 floats
            float v = slots[(size_t)row * 256 + t];
            float s = v, ss = v * v;
            #pragma unroll
            for (int o = 32; o > 0; o >>= 1) { s += __shfl_down(s, o); ss += __shfl_down(ss, o); }
            if ((t & 63) == 0) { red[t >> 6] = s; red[4 + (t >> 6)] = ss; }
            __syncthreads();
            float S = red[0] + red[1] + red[2] + red[3];
            float SS = red[4] + red[5] + red[6] + red[7];
            float mean = S * (1.f / 256.f);
            float var  = SS * (1.f / 256.f) - mean * mean;
            float rstd = rsqrtf(var + 1e-5f);
            lnr[t] = (v - mean) * rstd * g_s[t] + b_s[t];
            __syncthreads();
            const unsigned short* wr = Wq_bf + (size_t)t * 256;
            float acc = 0.f;
            #pragma unroll 4
            for (int d8 = 0; d8 < 32; ++d8) {
                uint4 ww = *(const uint4*)(wr + d8 * 8);
                const float* qq = lnr + d8 * 8;
                acc += bflo(ww.x) * qq[0] + bfhi(ww.x) * qq[1]
                     + bflo(ww.y) * qq[2] + bfhi(ww.y) * qq[3]
                     + bflo(ww.z) * qq[4] + bfhi(ww.z) * qq[5]
                     + bflo(ww.w) * qq[6] + bfhi(ww.w) * qq[7];
            }
            qbuf[(size_t)row * 256 + t] = acc;
            __syncthreads();
        }
        grid.sync();

        // -------- P3: dots + softmax(slots) + EPS + partial updates ---------
        // work = 16 chunks (64 tokens) x 32 batches
        for (int w = bid; w < 512; w += nB) {
            int chunk = w & 15, b = w >> 4, j0 = chunk * 64;
            float* q_s = (float*)smem;             // [8][260]
            float* d_s = (float*)(smem + 8320);    // [8][68]
            {
                int i = t >> 5, c0 = (t & 31) * 8;
                const float* qr = qbuf + (size_t)(b * 8 + i) * 256 + c0;
                *(float4*)(q_s + i * 260 + c0)     = *(const float4*)(qr);
                *(float4*)(q_s + i * 260 + c0 + 4) = *(const float4*)(qr + 4);
            }
            __syncthreads();
            {
                int i = t & 7, jj = t >> 3;
                const float* qd = q_s + i * 260;
                #pragma unroll
                for (int g = 0; g < 2; ++g) {
                    int jl = g * 32 + jj;
                    const unsigned short* krow = kv_bf + ((size_t)b * 1024 + j0 + jl) * 512;
                    float acc = 0.f;
                    #pragma unroll 4
                    for (int d8 = 0; d8 < 32; ++d8) {
                        uint4 kk = *(const uint4*)(krow + d8 * 8);
                        const float* qq = qd + d8 * 8;
                        acc += bflo(kk.x) * qq[0] + bfhi(kk.x) * qq[1]
                             + bflo(kk.y) * qq[2] + bfhi(kk.y) * qq[3]
                             + bflo(kk.z) * qq[4] + bfhi(kk.z) * qq[5]
                             + bflo(kk.w) * qq[6] + bfhi(kk.w) * qq[7];
                    }
                    d_s[i * 68 + jl] = acc * 0.0625f;   // SCALE
                }
            }
            __syncthreads();
            if (t < 64) {   // softmax over 8 slots for token t, + EPS
                float v[8], m = -1e30f;
                #pragma unroll
                for (int ii = 0; ii < 8; ii++) { v[ii] = d_s[ii * 68 + t]; m = fmaxf(m, v[ii]); }
                float s = 0.f;
                #pragma unroll
                for (int ii = 0; ii < 8; ii++) { v[ii] = __expf(v[ii] - m); s += v[ii]; }
                float inv = 1.f / s;
                #pragma unroll
                for (int ii = 0; ii < 8; ii++) d_s[ii * 68 + t] = v[ii] * inv + 1e-8f;
            }
            __syncthreads();
            if (t < 8) {
                float s = 0.f;
                #pragma unroll 8
                for (int jl = 0; jl < 64; ++jl) s += d_s[t * 68 + jl];
                rspart[((size_t)b * 16 + chunk) * 8 + t] = s;
            }
            {
                float acc8[8] = {0, 0, 0, 0, 0, 0, 0, 0};
                const unsigned short* vb = kv_bf + ((size_t)b * 1024 + j0) * 512 + 256 + t;
                for (int jl = 0; jl < 64; ++jl) {
                    float vv = bflo((unsigned int)vb[(size_t)jl * 512]) * 0.f + __uint_as_float((unsigned int)vb[(size_t)jl * 512] << 16);
                    #pragma unroll
                    for (int ii = 0; ii < 8; ii++) acc8[ii] += d_s[ii * 68 + jl] * vv;
                }
                float* up = upart + (((size_t)b * 16 + chunk) * 8) * 256 + t;
                #pragma unroll
                for (int ii = 0; ii < 8; ii++) up[ii * 256] = acc8[ii];
            }
            __syncthreads();
        }
        grid.sync();

        // -------- P4: combine partials, normalize; u_bf, h_bf ---------------
        for (int row = bid; row < 256; row += nB) {
            int b = row >> 3, i = row & 7;
            float acc = 0.f, rs = 0.f;
            #pragma unroll
            for (int c = 0; c < 16; ++c) {
                acc += upart[(((size_t)(b * 16 + c)) * 8 + i) * 256 + t];
                rs  += rspart[(size_t)(b * 16 + c) * 8 + i];
            }
            u_bf[(size_t)row * 256 + t] = f2bf(acc / rs);
            h_bf[(size_t)row * 256 + t] = f2bf(slots[(size_t)row * 256 + t]);
        }
        grid.sync();

        // -------- P5: gi = u@wih^T + bih ; gh = h@whh^T + bhh ---------------
        for (int w = bid; w < 96; w += nB) {
            int half = w >= 48 ? 1 : 0, tt = w - half * 48;
            int mt = tt / 12, nt = tt % 12;
            if (half == 0)
                gemm64_tile<1>(u_bf, wih_bf, gi, nullptr, bih, nullptr, nullptr, 0,
                               mt * 64, nt * 64, 768, 256, t, smem);
            else
                gemm64_tile<1>(h_bf, whh_bf, gh, nullptr, bhh, nullptr, nullptr, 0,
                               mt * 64, nt * 64, 768, 256, t, smem);
        }
        grid.sync();

        // -------- P6: GRU + LN_ff -> ff_bf ----------------------------------
        for (int row = bid; row < 256; row += nB) {
            float* red = (float*)smem;
            const float* gir = gi + (size_t)row * 768;
            const float* ghr = gh + (size_t)row * 768;
            float ir = gir[t], iz = gir[256 + t], in_ = gir[512 + t];
            float hr = ghr[t], hz = ghr[256 + t], hn  = ghr[512 + t];
            float r = 1.f / (1.f + __expf(-(ir + hr)));
            float z = 1.f / (1.f + __expf(-(iz + hz)));
            float a = in_ + r * hn;
            a = fminf(fmaxf(a, -15.f), 15.f);
            float e = __expf(2.f * a);
            float n = (e - 1.f) / (e + 1.f);
            float h = slots[(size_t)row * 256 + t];
            float s = (1.f - z) * n + z * h;
            slots[(size_t)row * 256 + t] = s;
            float sm = s, ssq = s * s;
            #pragma unroll
            for (int o = 32; o > 0; o >>= 1) { sm += __shfl_down(sm, o); ssq += __shfl_down(ssq, o); }
            if ((t & 63) == 0) { red[t >> 6] = sm; red[4 + (t >> 6)] = ssq; }
            __syncthreads();
            float S = red[0] + red[1] + red[2] + red[3];
            float SS = red[4] + red[5] + red[6] + red[7];
            float mean = S * (1.f / 256.f);
            float var  = SS * (1.f / 256.f) - mean * mean;
            float rstd = rsqrtf(var + 1e-5f);
            ff_bf[(size_t)row * 256 + t] = f2bf((s - mean) * rstd * g_ff[t] + b_ff[t]);
            __syncthreads();
        }
        grid.sync();

        // -------- P7: MLP1 (relu) -> h1_bf ----------------------------------
        for (int w = bid; w < 64; w += nB) {
            int mt = w >> 4, nt = w & 15;
            gemm64_tile<2>(ff_bf, w1_bf, nullptr, h1_bf, b1, nullptr, nullptr, 0,
                           mt * 64, nt * 64, 1024, 256, t, smem);
        }
        grid.sync();

        // -------- P8: MLP2 + residual -> slots (and d_out on last iter) -----
        for (int w = bid; w < 16; w += nB) {
            int mt = w >> 2, nt = w & 3;
            gemm64_tile<3>(h1_bf, w2_bf, nullptr, nullptr, b2, slots, out, it == 2 ? 1 : 0,
                           mt * 64, nt * 64, 256, 1024, t, smem);
        }
        grid.sync();
    }
}

// ---------------------------------------------------------------------------
extern "C" void kernel_launch(void* const* d_in, const int* in_sizes, int n_in,
                              void* d_out, int out_size, void* d_ws, size_t ws_size,
                              hipStream_t stream)
{
    const float* inputs = (const float*)d_in[0];
    const float* noise  = (const float*)d_in[1];
    const float* mu     = (const float*)d_in[2];
    const float* ls     = (const float*)d_in[3];
    const float* Wq     = (const float*)d_in[4];
    const float* Wk     = (const float*)d_in[5];
    const float* Wv     = (const float*)d_in[6];
    const float* wih    = (const float*)d_in[7];
    const float* whh    = (const float*)d_in[8];
    const float* bih    = (const float*)d_in[9];
    const float* bhh    = (const float*)d_in[10];
    const float* w1     = (const float*)d_in[11];
    const float* b1     = (const float*)d_in[12];
    const float* w2     = (const float*)d_in[13];
    const float* b2     = (const float*)d_in[14];
    const float* g_in   = (const float*)d_in[15];
    const float* b_in   = (const float*)d_in[16];
    const float* g_s    = (const float*)d_in[17];
    const float* b_s    = (const float*)d_in[18];
    const float* g_ff   = (const float*)d_in[19];
    const float* b_ff   = (const float*)d_in[20];
    float* out = (float*)d_out;
    char*  ws  = (char*)d_ws;

    void* args[] = { &inputs, &noise, &mu, &ls, &Wq, &Wk, &Wv, &wih, &whh,
                     &bih, &bhh, &w1, &b1, &w2, &b2, &g_in, &b_in, &g_s, &b_s,
                     &g_ff, &b_ff, &out, &ws };

    int maxB = 0;
    (void)hipOccupancyMaxActiveBlocksPerMultiprocessor(&maxB, mega_kernel, 256, 0);
    int perCU = maxB < 1 ? 1 : (maxB > 2 ? 2 : maxB);
    dim3 grid(256 * perCU), block(256);
    (void)hipLaunchCooperativeKernel((void*)mega_kernel, grid, block, args, 0, stream);
}

// Round 3
// 432.211 us; speedup vs baseline: 3.5906x; 3.5906x over previous
//
#include <hip/hip_runtime.h>

// ---------------------------------------------------------------------------
// SlotAttention on MI355X (gfx950). 8 launches, no grid.sync (round-2 showed
// cooperative grid.sync costs ~60us each on 8 XCDs -> barrier-bound).
// GEMMs in bf16 MFMA 16x16x32, everything else fp32 vector.
// Fragment layouts (learn_hip m89/m97, ref-verified):
//   A/B operand: idx = lane&15, k = (lane>>4)*8 + j  (8 contiguous bf16)
//   C/D:         col = lane&15, row = (lane>>4)*4 + reg
// LDS tiles use stride 264 (bf16) / 1032: 132%32==4, 516%32==4 -> worst 2-way
// bank aliasing (free per m136).
// ---------------------------------------------------------------------------

typedef __attribute__((ext_vector_type(8))) __bf16 bf16x8;
typedef __attribute__((ext_vector_type(4))) float  f32x4;

static __device__ __forceinline__ unsigned short f2bf(float f) {
    unsigned int x = __float_as_uint(f);
    x = (x + 0x7fffu + ((x >> 16) & 1u)) >> 16;   // RN-even
    return (unsigned short)x;
}
static __device__ __forceinline__ float bflo(unsigned int u) { return __uint_as_float(u << 16); }
static __device__ __forceinline__ float bfhi(unsigned int u) { return __uint_as_float(u & 0xffff0000u); }

// ---------------- K1: weights -> bf16, slots init, LN(inputs) -> bf16 -------
__global__ __launch_bounds__(256) void prep_kernel(
    const float* __restrict__ inputs, const float* __restrict__ noise,
    const float* __restrict__ mu, const float* __restrict__ ls,
    const float* __restrict__ Wq, const float* __restrict__ Wk,
    const float* __restrict__ Wv, const float* __restrict__ wih,
    const float* __restrict__ whh, const float* __restrict__ w1,
    const float* __restrict__ w2, const float* __restrict__ g_in,
    const float* __restrict__ b_in,
    unsigned short* __restrict__ x_bf, unsigned short* __restrict__ kvW_bf,
    unsigned short* __restrict__ Wq_bf, unsigned short* __restrict__ wih_bf,
    unsigned short* __restrict__ whh_bf, unsigned short* __restrict__ w1_bf,
    unsigned short* __restrict__ w2_bf, float* __restrict__ slots)
{
    const int blk = blockIdx.x, t = threadIdx.x;
    if (blk < 4608) {
        int g = blk * 256 + t;
        if      (g <   65536) kvW_bf[g]          = f2bf(Wk[g]);
        else if (g <  131072) kvW_bf[g]          = f2bf(Wv[g -   65536]);
        else if (g <  196608) Wq_bf[g - 131072]  = f2bf(Wq[g -  131072]);
        else if (g <  393216) wih_bf[g - 196608] = f2bf(wih[g - 196608]);
        else if (g <  589824) whh_bf[g - 393216] = f2bf(whh[g - 393216]);
        else if (g <  851968) w1_bf[g - 589824]  = f2bf(w1[g -  589824]);
        else if (g < 1114112) w2_bf[g - 851968]  = f2bf(w2[g -  851968]);
        else if (g < 1179648) {
            int i = g - 1114112, d = i & 255;
            slots[i] = mu[d] + __expf(ls[d]) * noise[i];
        }
    } else {
        // LN(inputs): one wave per row, 4 rows per block
        const int lane = t & 63;
        float4 g4  = *(const float4*)(g_in + lane * 4);
        float4 bb4 = *(const float4*)(b_in + lane * 4);
        int row = (blk - 4608) * 4 + (t >> 6);
        float4 v = *(const float4*)(inputs + (size_t)row * 256 + lane * 4);
        float s  = v.x + v.y + v.z + v.w;
        float ss = v.x * v.x + v.y * v.y + v.z * v.z + v.w * v.w;
        #pragma unroll
        for (int o = 32; o > 0; o >>= 1) { s += __shfl_xor(s, o); ss += __shfl_xor(ss, o); }
        float mean = s * (1.f / 256.f);
        float var  = ss * (1.f / 256.f) - mean * mean;
        float rstd = rsqrtf(var + 1e-5f);
        ushort4 o4;
        o4.x = f2bf((v.x - mean) * rstd * g4.x + bb4.x);
        o4.y = f2bf((v.y - mean) * rstd * g4.y + bb4.y);
        o4.z = f2bf((v.z - mean) * rstd * g4.z + bb4.z);
        o4.w = f2bf((v.w - mean) * rstd * g4.w + bb4.w);
        *(ushort4*)(x_bf + (size_t)row * 256 + lane * 4) = o4;
    }
}

// ---------------- K2: kv = x_ln @ [Wk;Wv]^T  (bf16 out) ---------------------
__global__ __launch_bounds__(256) void kv_gemm(
    const unsigned short* __restrict__ A, const unsigned short* __restrict__ B,
    unsigned short* __restrict__ C)   // M=32768, N=512, K=256
{
    __shared__ unsigned short As[128 * 32], Bs[128 * 32];
    const int m0 = blockIdx.x * 128, n0 = blockIdx.y * 128;
    const int t = threadIdx.x, wave = t >> 6, lane = t & 63;
    const int qr = (wave >> 1) * 64, qc = (wave & 1) * 64;
    const int lr = lane & 15, lq = lane >> 4;
    f32x4 acc[4][4] = {};
    const int sr = t >> 2, sc = (t & 3) * 8;
    for (int k0 = 0; k0 < 256; k0 += 32) {
        __syncthreads();
        uint4 a0 = *(const uint4*)(A + (size_t)(m0 + sr) * 256 + k0 + sc);
        uint4 a1 = *(const uint4*)(A + (size_t)(m0 + sr + 64) * 256 + k0 + sc);
        uint4 b0 = *(const uint4*)(B + (size_t)(n0 + sr) * 256 + k0 + sc);
        uint4 b1 = *(const uint4*)(B + (size_t)(n0 + sr + 64) * 256 + k0 + sc);
        *(uint4*)(As + sr * 32 + sc) = a0;
        *(uint4*)(As + (sr + 64) * 32 + sc) = a1;
        *(uint4*)(Bs + sr * 32 + sc) = b0;
        *(uint4*)(Bs + (sr + 64) * 32 + sc) = b1;
        __syncthreads();
        bf16x8 af[4], bv[4];
        #pragma unroll
        for (int i = 0; i < 4; i++) af[i] = *(const bf16x8*)(As + (qr + i * 16 + lr) * 32 + lq * 8);
        #pragma unroll
        for (int i = 0; i < 4; i++) bv[i] = *(const bf16x8*)(Bs + (qc + i * 16 + lr) * 32 + lq * 8);
        #pragma unroll
        for (int i = 0; i < 4; i++)
            #pragma unroll
            for (int j = 0; j < 4; j++)
                acc[i][j] = __builtin_amdgcn_mfma_f32_16x16x32_bf16(af[i], bv[j], acc[i][j], 0, 0, 0);
    }
    #pragma unroll
    for (int i = 0; i < 4; i++)
        #pragma unroll
        for (int j = 0; j < 4; j++) {
            int col = n0 + qc + j * 16 + lr;
            #pragma unroll
            for (int r = 0; r < 4; r++) {
                int row = m0 + qr + i * 16 + lq * 4 + r;
                C[(size_t)row * 512 + col] = f2bf(acc[i][j][r]);
            }
        }
}

// ---------------- K3: LN_s + q-proj (MFMA) + dots + softmax + partials ------
// grid (8 chunks of 128 tokens, 32 batches)
__global__ __launch_bounds__(256) void attn_kernel(
    const float* __restrict__ slots, const unsigned short* __restrict__ Wq_bf,
    const unsigned short* __restrict__ kv_bf, const float* __restrict__ g_s,
    const float* __restrict__ b_s, float* __restrict__ upart,
    float* __restrict__ rspart)
{
    __shared__ unsigned short s_bf[16 * 264];   // MFMA A (rows 8..15 zero)
    __shared__ float q_s[8 * 260];
    __shared__ float d_s[8 * 132];
    const int chunk = blockIdx.x, b = blockIdx.y, t = threadIdx.x;
    const int lane = t & 63, wave = t >> 6, lr = lane & 15, lq = lane >> 4;

    // LN over slots rows (32 threads per row, 8 elems each)
    {
        int i = t >> 5, c = (t & 31) * 8;
        const float* sr = slots + (size_t)(b * 8 + i) * 256 + c;
        float4 v0 = *(const float4*)sr, v1 = *(const float4*)(sr + 4);
        float s  = v0.x + v0.y + v0.z + v0.w + v1.x + v1.y + v1.z + v1.w;
        float ss = v0.x * v0.x + v0.y * v0.y + v0.z * v0.z + v0.w * v0.w
                 + v1.x * v1.x + v1.y * v1.y + v1.z * v1.z + v1.w * v1.w;
        #pragma unroll
        for (int o = 16; o > 0; o >>= 1) { s += __shfl_xor(s, o); ss += __shfl_xor(ss, o); }
        float mean = s * (1.f / 256.f);
        float var  = ss * (1.f / 256.f) - mean * mean;
        float rstd = rsqrtf(var + 1e-5f);
        float4 g0 = *(const float4*)(g_s + c), g1 = *(const float4*)(g_s + c + 4);
        float4 bb0 = *(const float4*)(b_s + c), bb1 = *(const float4*)(b_s + c + 4);
        ushort4 o0, o1;
        o0.x = f2bf((v0.x - mean) * rstd * g0.x + bb0.x);
        o0.y = f2bf((v0.y - mean) * rstd * g0.y + bb0.y);
        o0.z = f2bf((v0.z - mean) * rstd * g0.z + bb0.z);
        o0.w = f2bf((v0.w - mean) * rstd * g0.w + bb0.w);
        o1.x = f2bf((v1.x - mean) * rstd * g1.x + bb1.x);
        o1.y = f2bf((v1.y - mean) * rstd * g1.y + bb1.y);
        o1.z = f2bf((v1.z - mean) * rstd * g1.z + bb1.z);
        o1.w = f2bf((v1.w - mean) * rstd * g1.w + bb1.w);
        *(ushort4*)(s_bf + i * 264 + c)     = o0;
        *(ushort4*)(s_bf + i * 264 + c + 4) = o1;
    }
    for (int idx = t; idx < 8 * 264; idx += 256) s_bf[8 * 264 + idx] = 0;
    __syncthreads();

    // q = s_ln @ Wq^T via MFMA; B straight from global (L2-resident Wq)
    {
        f32x4 qa[4] = {};
        const int n0 = wave * 64;
        for (int k0 = 0; k0 < 256; k0 += 32) {
            bf16x8 af = *(const bf16x8*)(s_bf + lr * 264 + k0 + lq * 8);
            #pragma unroll
            for (int j = 0; j < 4; j++) {
                bf16x8 bv = *(const bf16x8*)(Wq_bf + (size_t)(n0 + j * 16 + lr) * 256 + k0 + lq * 8);
                qa[j] = __builtin_amdgcn_mfma_f32_16x16x32_bf16(af, bv, qa[j], 0, 0, 0);
            }
        }
        if (lq < 2) {
            #pragma unroll
            for (int j = 0; j < 4; j++)
                #pragma unroll
                for (int r = 0; r < 4; r++)
                    q_s[(lq * 4 + r) * 260 + n0 + j * 16 + lr] = qa[j][r] * 0.0625f; // fold SCALE
        }
    }
    __syncthreads();

    // dots: slot i vs 128 tokens of this chunk
    {
        int i = t & 7, jj = t >> 3, j0 = chunk * 128;
        const float4* qrow = (const float4*)(q_s + i * 260);
        #pragma unroll
        for (int g = 0; g < 4; g++) {
            int jl = g * 32 + jj;
            const unsigned short* krow = kv_bf + ((size_t)b * 1024 + j0 + jl) * 512;
            float acc = 0.f;
            #pragma unroll 4
            for (int d8 = 0; d8 < 32; ++d8) {
                uint4 kk = *(const uint4*)(krow + d8 * 8);
                float4 q0 = qrow[d8 * 2], q1 = qrow[d8 * 2 + 1];
                acc += bflo(kk.x) * q0.x + bfhi(kk.x) * q0.y
                     + bflo(kk.y) * q0.z + bfhi(kk.y) * q0.w
                     + bflo(kk.z) * q1.x + bfhi(kk.z) * q1.y
                     + bflo(kk.w) * q1.z + bfhi(kk.w) * q1.w;
            }
            d_s[i * 132 + jl] = acc;
        }
    }
    __syncthreads();
    if (t < 128) {   // softmax over 8 slots + EPS
        float v[8], m = -1e30f;
        #pragma unroll
        for (int ii = 0; ii < 8; ii++) { v[ii] = d_s[ii * 132 + t]; m = fmaxf(m, v[ii]); }
        float s = 0.f;
        #pragma unroll
        for (int ii = 0; ii < 8; ii++) { v[ii] = __expf(v[ii] - m); s += v[ii]; }
        float inv = 1.f / s;
        #pragma unroll
        for (int ii = 0; ii < 8; ii++) d_s[ii * 132 + t] = v[ii] * inv + 1e-8f;
    }
    __syncthreads();
    if (t < 8) {
        float s = 0.f;
        for (int jl = 0; jl < 128; ++jl) s += d_s[t * 132 + jl];
        rspart[((size_t)b * 8 + chunk) * 8 + t] = s;
    }
    {   // partial updates: acc[i] += attn[i][j] * v[j][d],  d = t
        float acc8[8] = {0, 0, 0, 0, 0, 0, 0, 0};
        const unsigned short* vb = kv_bf + ((size_t)b * 1024 + (size_t)chunk * 128) * 512 + 256 + t;
        for (int jl = 0; jl < 128; ++jl) {
            float vv = bflo((unsigned int)vb[(size_t)jl * 512]);
            #pragma unroll
            for (int ii = 0; ii < 8; ii++) acc8[ii] += d_s[ii * 132 + jl] * vv;
        }
        float* up = upart + (((size_t)b * 8 + chunk) * 8) * 256 + t;
        #pragma unroll
        for (int ii = 0; ii < 8; ii++) up[ii * 256] = acc8[ii];
    }
}

// ---------------- K4: combine + gi/gh + GRU + LN_ff + MLP (full MFMA) -------
// 32 blocks (one per batch, 8 slot-rows), 256 threads.
__global__ __launch_bounds__(256) void slot_kernel(
    const float* __restrict__ upart, const float* __restrict__ rspart,
    float* __restrict__ slots,
    const unsigned short* __restrict__ wih_bf, const unsigned short* __restrict__ whh_bf,
    const unsigned short* __restrict__ w1_bf, const unsigned short* __restrict__ w2_bf,
    const float* __restrict__ bih, const float* __restrict__ bhh,
    const float* __restrict__ b1, const float* __restrict__ b2,
    const float* __restrict__ g_ff, const float* __restrict__ b_ff,
    float* __restrict__ out, int fin)
{
    __shared__ unsigned short uA[16 * 264];     // updates (A operand)
    __shared__ unsigned short hA[16 * 264];     // slots_prev (A operand)
    __shared__ unsigned short fA[16 * 264];     // LN_ff out (A operand)
    __shared__ unsigned short h1A[16 * 1032];   // mlp hidden (A operand)
    __shared__ float sbuf[8 * 264];             // new slots (pre-mlp) f32
    __shared__ float rs_sh[8];
    const int b = blockIdx.x, t = threadIdx.x;
    const int lane = t & 63, wave = t >> 6, lr = lane & 15, lq = lane >> 4;

    for (int idx = t; idx < 8 * 264; idx += 256) {
        uA[8 * 264 + idx] = 0; hA[8 * 264 + idx] = 0; fA[8 * 264 + idx] = 0;
    }
    for (int idx = t; idx < 8 * 1032; idx += 256) h1A[8 * 1032 + idx] = 0;
    if (t < 8) {
        float r = 0.f;
        #pragma unroll
        for (int c = 0; c < 8; c++) r += rspart[((size_t)b * 8 + c) * 8 + t];
        rs_sh[t] = r;
    }
    __syncthreads();
    for (int idx = t; idx < 2048; idx += 256) {
        int i = idx >> 8, d = idx & 255;
        float acc = 0.f;
        #pragma unroll
        for (int c = 0; c < 8; c++) acc += upart[(((size_t)b * 8 + c) * 8 + i) * 256 + d];
        uA[i * 264 + d] = f2bf(acc / rs_sh[i]);
        hA[i * 264 + d] = f2bf(slots[(size_t)(b * 8 + i) * 256 + d]);
    }
    __syncthreads();

    // gi = u @ wih^T, gh = h @ whh^T : wave w owns e in [w*64, w*64+64)
    f32x4 gia[12] = {}, gha[12] = {};
    const int ew = wave * 64;
    for (int k0 = 0; k0 < 256; k0 += 32) {
        bf16x8 au = *(const bf16x8*)(uA + lr * 264 + k0 + lq * 8);
        bf16x8 ah = *(const bf16x8*)(hA + lr * 264 + k0 + lq * 8);
        #pragma unroll
        for (int g = 0; g < 3; g++)
            #pragma unroll
            for (int j = 0; j < 4; j++) {
                int n = g * 256 + ew + j * 16 + lr;
                bf16x8 bi_ = *(const bf16x8*)(wih_bf + (size_t)n * 256 + k0 + lq * 8);
                bf16x8 bh_ = *(const bf16x8*)(whh_bf + (size_t)n * 256 + k0 + lq * 8);
                gia[g * 4 + j] = __builtin_amdgcn_mfma_f32_16x16x32_bf16(au, bi_, gia[g * 4 + j], 0, 0, 0);
                gha[g * 4 + j] = __builtin_amdgcn_mfma_f32_16x16x32_bf16(ah, bh_, gha[g * 4 + j], 0, 0, 0);
            }
    }
    // GRU epilogue (in-register: gi/gh frag layouts match lane-for-lane)
    #pragma unroll
    for (int j = 0; j < 4; j++) {
        int e = ew + j * 16 + lr;
        float bir = bih[e], biz = bih[256 + e], bin = bih[512 + e];
        float bhr = bhh[e], bhz = bhh[256 + e], bhn = bhh[512 + e];
        #pragma unroll
        for (int r = 0; r < 4; r++) {
            int row = lq * 4 + r;
            if (row < 8) {
                float ir = gia[j][r] + bir, iz = gia[4 + j][r] + biz, in_ = gia[8 + j][r] + bin;
                float hr = gha[j][r] + bhr, hz = gha[4 + j][r] + bhz, hn = gha[8 + j][r] + bhn;
                float rg = 1.f / (1.f + __expf(-(ir + hr)));
                float z  = 1.f / (1.f + __expf(-(iz + hz)));
                float a = in_ + rg * hn;
                a = fminf(fmaxf(a, -15.f), 15.f);
                float ee = __expf(2.f * a);
                float nn = (ee - 1.f) / (ee + 1.f);
                float h = slots[(size_t)(b * 8 + row) * 256 + e];
                sbuf[row * 264 + e] = (1.f - z) * nn + z * h;
            }
        }
    }
    __syncthreads();

    // LN_ff -> fA (bf16)
    {
        int i = t >> 5, c = (t & 31) * 8;
        const float* sr = sbuf + i * 264 + c;
        float4 v0 = *(const float4*)sr, v1 = *(const float4*)(sr + 4);
        float s  = v0.x + v0.y + v0.z + v0.w + v1.x + v1.y + v1.z + v1.w;
        float ss = v0.x * v0.x + v0.y * v0.y + v0.z * v0.z + v0.w * v0.w
                 + v1.x * v1.x + v1.y * v1.y + v1.z * v1.z + v1.w * v1.w;
        #pragma unroll
        for (int o = 16; o > 0; o >>= 1) { s += __shfl_xor(s, o); ss += __shfl_xor(ss, o); }
        float mean = s * (1.f / 256.f);
        float var  = ss * (1.f / 256.f) - mean * mean;
        float rstd = rsqrtf(var + 1e-5f);
        float4 g0 = *(const float4*)(g_ff + c), g1 = *(const float4*)(g_ff + c + 4);
        float4 bb0 = *(const float4*)(b_ff + c), bb1 = *(const float4*)(b_ff + c + 4);
        ushort4 o0, o1;
        o0.x = f2bf((v0.x - mean) * rstd * g0.x + bb0.x);
        o0.y = f2bf((v0.y - mean) * rstd * g0.y + bb0.y);
        o0.z = f2bf((v0.z - mean) * rstd * g0.z + bb0.z);
        o0.w = f2bf((v0.w - mean) * rstd * g0.w + bb0.w);
        o1.x = f2bf((v1.x - mean) * rstd * g1.x + bb1.x);
        o1.y = f2bf((v1.y - mean) * rstd * g1.y + bb1.y);
        o1.z = f2bf((v1.z - mean) * rstd * g1.z + bb1.z);
        o1.w = f2bf((v1.w - mean) * rstd * g1.w + bb1.w);
        *(ushort4*)(fA + i * 264 + c)     = o0;
        *(ushort4*)(fA + i * 264 + c + 4) = o1;
    }
    __syncthreads();

    // MLP1: h1 = relu(ff @ w1^T + b1); wave w owns n in [w*256, w*256+256)
    {
        f32x4 m1[16] = {};
        const int nb = wave * 256;
        for (int k0 = 0; k0 < 256; k0 += 32) {
            bf16x8 af = *(const bf16x8*)(fA + lr * 264 + k0 + lq * 8);
            #pragma unroll
            for (int j = 0; j < 16; j++) {
                bf16x8 bv = *(const bf16x8*)(w1_bf + (size_t)(nb + j * 16 + lr) * 256 + k0 + lq * 8);
                m1[j] = __builtin_amdgcn_mfma_f32_16x16x32_bf16(af, bv, m1[j], 0, 0, 0);
            }
        }
        #pragma unroll
        for (int j = 0; j < 16; j++) {
            int n = nb + j * 16 + lr;
            float bb = b1[n];
            if (lq < 2) {
                #pragma unroll
                for (int r = 0; r < 4; r++)
                    h1A[(lq * 4 + r) * 1032 + n] = f2bf(fmaxf(m1[j][r] + bb, 0.f));
            }
        }
    }
    __syncthreads();

    // MLP2 + residual: wave w owns e in [w*64, w*64+64)
    {
        f32x4 m2[4] = {};
        const int nb = wave * 64;
        for (int k0 = 0; k0 < 1024; k0 += 32) {
            bf16x8 af = *(const bf16x8*)(h1A + lr * 1032 + k0 + lq * 8);
            #pragma unroll
            for (int j = 0; j < 4; j++) {
                bf16x8 bv = *(const bf16x8*)(w2_bf + (size_t)(nb + j * 16 + lr) * 1024 + k0 + lq * 8);
                m2[j] = __builtin_amdgcn_mfma_f32_16x16x32_bf16(af, bv, m2[j], 0, 0, 0);
            }
        }
        #pragma unroll
        for (int j = 0; j < 4; j++) {
            int e = nb + j * 16 + lr;
            float bb = b2[e];
            if (lq < 2) {
                #pragma unroll
                for (int r = 0; r < 4; r++) {
                    int row = lq * 4 + r;
                    float val = m2[j][r] + bb + sbuf[row * 264 + e];
                    slots[(size_t)(b * 8 + row) * 256 + e] = val;
                    if (fin) out[(size_t)(b * 8 + row) * 256 + e] = val;
                }
            }
        }
    }
}

// ---------------------------------------------------------------------------
extern "C" void kernel_launch(void* const* d_in, const int* in_sizes, int n_in,
                              void* d_out, int out_size, void* d_ws, size_t ws_size,
                              hipStream_t stream)
{
    const float* inputs = (const float*)d_in[0];
    const float* noise  = (const float*)d_in[1];
    const float* mu     = (const float*)d_in[2];
    const float* ls     = (const float*)d_in[3];
    const float* Wq     = (const float*)d_in[4];
    const float* Wk     = (const float*)d_in[5];
    const float* Wv     = (const float*)d_in[6];
    const float* wih    = (const float*)d_in[7];
    const float* whh    = (const float*)d_in[8];
    const float* bih    = (const float*)d_in[9];
    const float* bhh    = (const float*)d_in[10];
    const float* w1     = (const float*)d_in[11];
    const float* b1     = (const float*)d_in[12];
    const float* w2     = (const float*)d_in[13];
    const float* b2     = (const float*)d_in[14];
    const float* g_in   = (const float*)d_in[15];
    const float* b_in   = (const float*)d_in[16];
    const float* g_s    = (const float*)d_in[17];
    const float* b_s    = (const float*)d_in[18];
    const float* g_ff   = (const float*)d_in[19];
    const float* b_ff   = (const float*)d_in[20];
    float* out = (float*)d_out;
    char*  ws  = (char*)d_ws;

    unsigned short* x_bf   = (unsigned short*)(ws + 0);
    unsigned short* kv_bf  = (unsigned short*)(ws + 16777216);
    unsigned short* kvW_bf = (unsigned short*)(ws + 50331648);
    unsigned short* Wq_bf  = (unsigned short*)(ws + 50593792);
    unsigned short* wih_bf = (unsigned short*)(ws + 50724864);
    unsigned short* whh_bf = (unsigned short*)(ws + 51118080);
    unsigned short* w1_bf  = (unsigned short*)(ws + 51511296);
    unsigned short* w2_bf  = (unsigned short*)(ws + 52035584);
    float*          slots  = (float*)(ws + 52559872);
    float*          upart  = (float*)(ws + 52822016);
    float*          rspart = (float*)(ws + 54919168);

    prep_kernel<<<12800, 256, 0, stream>>>(inputs, noise, mu, ls, Wq, Wk, Wv,
                                           wih, whh, w1, w2, g_in, b_in,
                                           x_bf, kvW_bf, Wq_bf, wih_bf, whh_bf,
                                           w1_bf, w2_bf, slots);
    kv_gemm<<<dim3(256, 4), 256, 0, stream>>>(x_bf, kvW_bf, kv_bf);
    for (int it = 0; it < 3; ++it) {
        attn_kernel<<<dim3(8, 32), 256, 0, stream>>>(slots, Wq_bf, kv_bf, g_s, b_s,
                                                     upart, rspart);
        slot_kernel<<<32, 256, 0, stream>>>(upart, rspart, slots,
                                            wih_bf, whh_bf, w1_bf, w2_bf,
                                            bih, bhh, b1, b2, g_ff, b_ff,
                                            out, it == 2 ? 1 : 0);
    }
}

// Round 4
// 373.779 us; speedup vs baseline: 4.1519x; 1.1563x over previous
//
#include <hip/hip_runtime.h>

// ---------------------------------------------------------------------------
// SlotAttention on MI355X (gfx950). 8 launches, no grid.sync.
// R4: slot_kernel widened to 1024 threads (16 waves) — R3 showed it was
// latency-bound at 32 blocks x 4 waves (Occ 1.3%, VALUBusy 0.8%, 73us).
// attn: 512 blocks (64-token chunks) + V staged in LDS (was scalar strided
// global loads).
// Fragment layouts (learn_hip m89/m97, ref-verified):
//   A/B operand: idx = lane&15, k = (lane>>4)*8 + j  (8 contiguous bf16)
//   C/D:         col = lane&15, row = (lane>>4)*4 + reg
// ---------------------------------------------------------------------------

typedef __attribute__((ext_vector_type(8))) __bf16 bf16x8;
typedef __attribute__((ext_vector_type(4))) float  f32x4;

static __device__ __forceinline__ unsigned short f2bf(float f) {
    unsigned int x = __float_as_uint(f);
    x = (x + 0x7fffu + ((x >> 16) & 1u)) >> 16;   // RN-even
    return (unsigned short)x;
}
static __device__ __forceinline__ float bflo(unsigned int u) { return __uint_as_float(u << 16); }
static __device__ __forceinline__ float bfhi(unsigned int u) { return __uint_as_float(u & 0xffff0000u); }

// ---------------- K1: weights -> bf16, slots init, LN(inputs) -> bf16 -------
__global__ __launch_bounds__(256) void prep_kernel(
    const float* __restrict__ inputs, const float* __restrict__ noise,
    const float* __restrict__ mu, const float* __restrict__ ls,
    const float* __restrict__ Wq, const float* __restrict__ Wk,
    const float* __restrict__ Wv, const float* __restrict__ wih,
    const float* __restrict__ whh, const float* __restrict__ w1,
    const float* __restrict__ w2, const float* __restrict__ g_in,
    const float* __restrict__ b_in,
    unsigned short* __restrict__ x_bf, unsigned short* __restrict__ kvW_bf,
    unsigned short* __restrict__ Wq_bf, unsigned short* __restrict__ wih_bf,
    unsigned short* __restrict__ whh_bf, unsigned short* __restrict__ w1_bf,
    unsigned short* __restrict__ w2_bf, float* __restrict__ slots)
{
    const int blk = blockIdx.x, t = threadIdx.x;
    if (blk < 4608) {
        int g = blk * 256 + t;
        if      (g <   65536) kvW_bf[g]          = f2bf(Wk[g]);
        else if (g <  131072) kvW_bf[g]          = f2bf(Wv[g -   65536]);
        else if (g <  196608) Wq_bf[g - 131072]  = f2bf(Wq[g -  131072]);
        else if (g <  393216) wih_bf[g - 196608] = f2bf(wih[g - 196608]);
        else if (g <  589824) whh_bf[g - 393216] = f2bf(whh[g - 393216]);
        else if (g <  851968) w1_bf[g - 589824]  = f2bf(w1[g -  589824]);
        else if (g < 1114112) w2_bf[g - 851968]  = f2bf(w2[g -  851968]);
        else if (g < 1179648) {
            int i = g - 1114112, d = i & 255;
            slots[i] = mu[d] + __expf(ls[d]) * noise[i];
        }
    } else {
        const int lane = t & 63;
        float4 g4  = *(const float4*)(g_in + lane * 4);
        float4 bb4 = *(const float4*)(b_in + lane * 4);
        int row = (blk - 4608) * 4 + (t >> 6);
        float4 v = *(const float4*)(inputs + (size_t)row * 256 + lane * 4);
        float s  = v.x + v.y + v.z + v.w;
        float ss = v.x * v.x + v.y * v.y + v.z * v.z + v.w * v.w;
        #pragma unroll
        for (int o = 32; o > 0; o >>= 1) { s += __shfl_xor(s, o); ss += __shfl_xor(ss, o); }
        float mean = s * (1.f / 256.f);
        float var  = ss * (1.f / 256.f) - mean * mean;
        float rstd = rsqrtf(var + 1e-5f);
        ushort4 o4;
        o4.x = f2bf((v.x - mean) * rstd * g4.x + bb4.x);
        o4.y = f2bf((v.y - mean) * rstd * g4.y + bb4.y);
        o4.z = f2bf((v.z - mean) * rstd * g4.z + bb4.z);
        o4.w = f2bf((v.w - mean) * rstd * g4.w + bb4.w);
        *(ushort4*)(x_bf + (size_t)row * 256 + lane * 4) = o4;
    }
}

// ---------------- K2: kv = x_ln @ [Wk;Wv]^T  (bf16 out) ---------------------
__global__ __launch_bounds__(256) void kv_gemm(
    const unsigned short* __restrict__ A, const unsigned short* __restrict__ B,
    unsigned short* __restrict__ C)   // M=32768, N=512, K=256
{
    __shared__ unsigned short As[128 * 32], Bs[128 * 32];
    const int m0 = blockIdx.x * 128, n0 = blockIdx.y * 128;
    const int t = threadIdx.x, wave = t >> 6, lane = t & 63;
    const int qr = (wave >> 1) * 64, qc = (wave & 1) * 64;
    const int lr = lane & 15, lq = lane >> 4;
    f32x4 acc[4][4] = {};
    const int sr = t >> 2, sc = (t & 3) * 8;
    for (int k0 = 0; k0 < 256; k0 += 32) {
        __syncthreads();
        uint4 a0 = *(const uint4*)(A + (size_t)(m0 + sr) * 256 + k0 + sc);
        uint4 a1 = *(const uint4*)(A + (size_t)(m0 + sr + 64) * 256 + k0 + sc);
        uint4 b0 = *(const uint4*)(B + (size_t)(n0 + sr) * 256 + k0 + sc);
        uint4 b1 = *(const uint4*)(B + (size_t)(n0 + sr + 64) * 256 + k0 + sc);
        *(uint4*)(As + sr * 32 + sc) = a0;
        *(uint4*)(As + (sr + 64) * 32 + sc) = a1;
        *(uint4*)(Bs + sr * 32 + sc) = b0;
        *(uint4*)(Bs + (sr + 64) * 32 + sc) = b1;
        __syncthreads();
        bf16x8 af[4], bv[4];
        #pragma unroll
        for (int i = 0; i < 4; i++) af[i] = *(const bf16x8*)(As + (qr + i * 16 + lr) * 32 + lq * 8);
        #pragma unroll
        for (int i = 0; i < 4; i++) bv[i] = *(const bf16x8*)(Bs + (qc + i * 16 + lr) * 32 + lq * 8);
        #pragma unroll
        for (int i = 0; i < 4; i++)
            #pragma unroll
            for (int j = 0; j < 4; j++)
                acc[i][j] = __builtin_amdgcn_mfma_f32_16x16x32_bf16(af[i], bv[j], acc[i][j], 0, 0, 0);
    }
    #pragma unroll
    for (int i = 0; i < 4; i++)
        #pragma unroll
        for (int j = 0; j < 4; j++) {
            int col = n0 + qc + j * 16 + lr;
            #pragma unroll
            for (int r = 0; r < 4; r++) {
                int row = m0 + qr + i * 16 + lq * 4 + r;
                C[(size_t)row * 512 + col] = f2bf(acc[i][j][r]);
            }
        }
}

// ---------------- K3: LN_s + q-proj (MFMA) + dots + softmax + partials ------
// grid (16 chunks of 64 tokens, 32 batches), 256 threads.
__global__ __launch_bounds__(256) void attn_kernel(
    const float* __restrict__ slots, const unsigned short* __restrict__ Wq_bf,
    const unsigned short* __restrict__ kv_bf, const float* __restrict__ g_s,
    const float* __restrict__ b_s, float* __restrict__ upart,
    float* __restrict__ rspart)
{
    __shared__ unsigned short s_bf[16 * 264];   // MFMA A (rows 8..15 zero)
    __shared__ float q_s[8 * 260];
    __shared__ float d_s[8 * 68];
    __shared__ unsigned short v_s[64 * 264];    // staged V chunk
    const int chunk = blockIdx.x, b = blockIdx.y, t = threadIdx.x;
    const int lane = t & 63, wave = t >> 6, lr = lane & 15, lq = lane >> 4;
    const int j0 = chunk * 64;

    // LN over slots rows (32 threads per row)
    {
        int i = t >> 5, c = (t & 31) * 8;
        const float* sr = slots + (size_t)(b * 8 + i) * 256 + c;
        float4 v0 = *(const float4*)sr, v1 = *(const float4*)(sr + 4);
        float s  = v0.x + v0.y + v0.z + v0.w + v1.x + v1.y + v1.z + v1.w;
        float ss = v0.x * v0.x + v0.y * v0.y + v0.z * v0.z + v0.w * v0.w
                 + v1.x * v1.x + v1.y * v1.y + v1.z * v1.z + v1.w * v1.w;
        #pragma unroll
        for (int o = 16; o > 0; o >>= 1) { s += __shfl_xor(s, o); ss += __shfl_xor(ss, o); }
        float mean = s * (1.f / 256.f);
        float var  = ss * (1.f / 256.f) - mean * mean;
        float rstd = rsqrtf(var + 1e-5f);
        float4 g0 = *(const float4*)(g_s + c), g1 = *(const float4*)(g_s + c + 4);
        float4 bb0 = *(const float4*)(b_s + c), bb1 = *(const float4*)(b_s + c + 4);
        ushort4 o0, o1;
        o0.x = f2bf((v0.x - mean) * rstd * g0.x + bb0.x);
        o0.y = f2bf((v0.y - mean) * rstd * g0.y + bb0.y);
        o0.z = f2bf((v0.z - mean) * rstd * g0.z + bb0.z);
        o0.w = f2bf((v0.w - mean) * rstd * g0.w + bb0.w);
        o1.x = f2bf((v1.x - mean) * rstd * g1.x + bb1.x);
        o1.y = f2bf((v1.y - mean) * rstd * g1.y + bb1.y);
        o1.z = f2bf((v1.z - mean) * rstd * g1.z + bb1.z);
        o1.w = f2bf((v1.w - mean) * rstd * g1.w + bb1.w);
        *(ushort4*)(s_bf + i * 264 + c)     = o0;
        *(ushort4*)(s_bf + i * 264 + c + 4) = o1;
    }
    for (int idx = t; idx < 8 * 264; idx += 256) s_bf[8 * 264 + idx] = 0;
    // stage V chunk (64 tokens x 256) coalesced
    #pragma unroll
    for (int p = 0; p < 8; ++p) {
        int idx = t + p * 256;               // 2048 uint4 total
        int token = idx >> 5, c8 = (idx & 31) * 8;
        *(uint4*)(v_s + token * 264 + c8) =
            *(const uint4*)(kv_bf + ((size_t)b * 1024 + j0 + token) * 512 + 256 + c8);
    }
    __syncthreads();

    // q = s_ln @ Wq^T via MFMA (Wq L2-resident), fold SCALE
    {
        f32x4 qa[4] = {};
        const int n0 = wave * 64;
        for (int k0 = 0; k0 < 256; k0 += 32) {
            bf16x8 af = *(const bf16x8*)(s_bf + lr * 264 + k0 + lq * 8);
            #pragma unroll
            for (int j = 0; j < 4; j++) {
                bf16x8 bv = *(const bf16x8*)(Wq_bf + (size_t)(n0 + j * 16 + lr) * 256 + k0 + lq * 8);
                qa[j] = __builtin_amdgcn_mfma_f32_16x16x32_bf16(af, bv, qa[j], 0, 0, 0);
            }
        }
        if (lq < 2) {
            #pragma unroll
            for (int j = 0; j < 4; j++)
                #pragma unroll
                for (int r = 0; r < 4; r++)
                    q_s[(lq * 4 + r) * 260 + n0 + j * 16 + lr] = qa[j][r] * 0.0625f;
        }
    }
    __syncthreads();

    // dots: slot i vs 64 tokens (k from global; 8-lane broadcast per row)
    {
        int i = t & 7, jj = t >> 3;          // jj in [0,32)
        const float4* qrow = (const float4*)(q_s + i * 260);
        #pragma unroll
        for (int g = 0; g < 2; g++) {
            int jl = g * 32 + jj;
            const unsigned short* krow = kv_bf + ((size_t)b * 1024 + j0 + jl) * 512;
            float acc = 0.f;
            #pragma unroll 4
            for (int d8 = 0; d8 < 32; ++d8) {
                uint4 kk = *(const uint4*)(krow + d8 * 8);
                float4 qv0 = qrow[d8 * 2], qv1 = qrow[d8 * 2 + 1];
                acc += bflo(kk.x) * qv0.x + bfhi(kk.x) * qv0.y
                     + bflo(kk.y) * qv0.z + bfhi(kk.y) * qv0.w
                     + bflo(kk.z) * qv1.x + bfhi(kk.z) * qv1.y
                     + bflo(kk.w) * qv1.z + bfhi(kk.w) * qv1.w;
            }
            d_s[i * 68 + jl] = acc;
        }
    }
    __syncthreads();
    if (t < 64) {   // softmax over 8 slots + EPS
        float v[8], m = -1e30f;
        #pragma unroll
        for (int ii = 0; ii < 8; ii++) { v[ii] = d_s[ii * 68 + t]; m = fmaxf(m, v[ii]); }
        float s = 0.f;
        #pragma unroll
        for (int ii = 0; ii < 8; ii++) { v[ii] = __expf(v[ii] - m); s += v[ii]; }
        float inv = 1.f / s;
        #pragma unroll
        for (int ii = 0; ii < 8; ii++) d_s[ii * 68 + t] = v[ii] * inv + 1e-8f;
    }
    __syncthreads();
    if (t < 8) {
        float s = 0.f;
        #pragma unroll 8
        for (int jl = 0; jl < 64; ++jl) s += d_s[t * 68 + jl];
        rspart[((size_t)b * 16 + chunk) * 8 + t] = s;
    }
    {   // partial updates from LDS-staged V: acc[i] += attn[i][j]*v[j][d], d=t
        float acc8[8] = {0, 0, 0, 0, 0, 0, 0, 0};
        #pragma unroll 4
        for (int jl = 0; jl < 64; ++jl) {
            float vv = bflo((unsigned int)v_s[jl * 264 + t]);
            #pragma unroll
            for (int ii = 0; ii < 8; ii++) acc8[ii] += d_s[ii * 68 + jl] * vv;
        }
        float* up = upart + (((size_t)b * 16 + chunk) * 8) * 256 + t;
        #pragma unroll
        for (int ii = 0; ii < 8; ii++) up[ii * 256] = acc8[ii];
    }
}

// ---------------- K4: combine + gi/gh + GRU + LN_ff + MLP (full MFMA) -------
// 32 blocks (one per batch), 1024 threads = 16 waves.
__global__ __launch_bounds__(1024) void slot_kernel(
    const float* __restrict__ upart, const float* __restrict__ rspart,
    float* __restrict__ slots,
    const unsigned short* __restrict__ wih_bf, const unsigned short* __restrict__ whh_bf,
    const unsigned short* __restrict__ w1_bf, const unsigned short* __restrict__ w2_bf,
    const float* __restrict__ bih, const float* __restrict__ bhh,
    const float* __restrict__ b1, const float* __restrict__ b2,
    const float* __restrict__ g_ff, const float* __restrict__ b_ff,
    float* __restrict__ out, int fin)
{
    __shared__ unsigned short uA[16 * 264];   // updates, A-layout (rows 8..15 zero)
    __shared__ unsigned short hA[16 * 264];   // slots_prev, A-layout
    __shared__ float sbuf[8 * 264];           // new slots (pre-MLP) f32
    __shared__ float gsc[12416];              // gis/ghs (f32) ALIASED with fA/h1A (bf16)
    __shared__ float redS[16], redSS[16];
    __shared__ float rs_sh[8];
    float* gis = gsc;                         // [8][776]
    float* ghs = gsc + 6208;                  // [8][776]
    unsigned short* fA  = (unsigned short*)gsc;      // [16][264] after GRU
    unsigned short* h1A = fA + 16 * 264;             // [16][1032]

    const int b = blockIdx.x, t = threadIdx.x;
    const int lane = t & 63, wave = t >> 6, lr = lane & 15, lq = lane >> 4;

    // zero A-pads, combine rs
    for (int idx = t; idx < 8 * 264; idx += 1024) { uA[8 * 264 + idx] = 0; hA[8 * 264 + idx] = 0; }
    if (t < 8) {
        float r = 0.f;
        #pragma unroll
        for (int c = 0; c < 16; c++) r += rspart[((size_t)b * 16 + c) * 8 + t];
        rs_sh[t] = r;
    }
    __syncthreads();
    // combine partials -> uA, slots_prev -> hA
    for (int idx = t; idx < 2048; idx += 1024) {
        int i = idx >> 8, d = idx & 255;
        float acc = 0.f;
        #pragma unroll
        for (int c = 0; c < 16; c++) acc += upart[(((size_t)b * 16 + c) * 8 + i) * 256 + d];
        uA[i * 264 + d] = f2bf(acc / rs_sh[i]);
        hA[i * 264 + d] = f2bf(slots[(size_t)(b * 8 + i) * 256 + d]);
    }
    __syncthreads();

    // gi/gh GEMM: 16 waves; w<8 -> gi cols [w*96,w*96+96), w>=8 -> gh
    {
        const int isg = wave >> 3, cb = (wave & 7) * 96;
        const unsigned short* XA = isg ? hA : uA;
        const unsigned short* W  = isg ? whh_bf : wih_bf;
        float* G = isg ? ghs : gis;
        f32x4 acc[6] = {};
        for (int k0 = 0; k0 < 256; k0 += 32) {
            bf16x8 af = *(const bf16x8*)(XA + lr * 264 + k0 + lq * 8);
            #pragma unroll
            for (int j = 0; j < 6; j++) {
                bf16x8 bv = *(const bf16x8*)(W + (size_t)(cb + j * 16 + lr) * 256 + k0 + lq * 8);
                acc[j] = __builtin_amdgcn_mfma_f32_16x16x32_bf16(af, bv, acc[j], 0, 0, 0);
            }
        }
        if (lq < 2) {
            #pragma unroll
            for (int j = 0; j < 6; j++)
                #pragma unroll
                for (int r = 0; r < 4; r++)
                    G[(lq * 4 + r) * 776 + cb + j * 16 + lr] = acc[j][r];
        }
    }
    __syncthreads();

    // GRU (2 elems/thread) + LN stats
    const int grow = t >> 7, gd = (t & 127) * 2;
    float sv0, sv1, mean, rstd;
    {
        float sm = 0.f, ssq = 0.f, svq[2];
        #pragma unroll
        for (int q = 0; q < 2; q++) {
            int d = gd + q;
            float ir = gis[grow * 776 + d]       + bih[d];
            float iz = gis[grow * 776 + 256 + d] + bih[256 + d];
            float in_= gis[grow * 776 + 512 + d] + bih[512 + d];
            float hr = ghs[grow * 776 + d]       + bhh[d];
            float hz = ghs[grow * 776 + 256 + d] + bhh[256 + d];
            float hn = ghs[grow * 776 + 512 + d] + bhh[512 + d];
            float rg = 1.f / (1.f + __expf(-(ir + hr)));
            float z  = 1.f / (1.f + __expf(-(iz + hz)));
            float a = in_ + rg * hn;
            a = fminf(fmaxf(a, -15.f), 15.f);
            float e = __expf(2.f * a);
            float nn = (e - 1.f) / (e + 1.f);
            float h = slots[(size_t)(b * 8 + grow) * 256 + d];
            float s = (1.f - z) * nn + z * h;
            sbuf[grow * 264 + d] = s;
            svq[q] = s; sm += s; ssq += s * s;
        }
        sv0 = svq[0]; sv1 = svq[1];
        #pragma unroll
        for (int o = 32; o > 0; o >>= 1) { sm += __shfl_xor(sm, o); ssq += __shfl_xor(ssq, o); }
        if (lane == 0) { redS[wave] = sm; redSS[wave] = ssq; }
    }
    __syncthreads();   // gis/ghs dead from here; region becomes fA/h1A
    {
        float S  = redS[grow * 2] + redS[grow * 2 + 1];
        float SS = redSS[grow * 2] + redSS[grow * 2 + 1];
        mean = S * (1.f / 256.f);
        float var = SS * (1.f / 256.f) - mean * mean;
        rstd = rsqrtf(var + 1e-5f);
    }
    // zero pads + LN_ff apply -> fA
    for (int idx = t; idx < 8 * 264; idx += 1024) fA[8 * 264 + idx] = 0;
    for (int idx = t; idx < 8 * 1032; idx += 1024) h1A[8 * 1032 + idx] = 0;
    fA[grow * 264 + gd]     = f2bf((sv0 - mean) * rstd * g_ff[gd]     + b_ff[gd]);
    fA[grow * 264 + gd + 1] = f2bf((sv1 - mean) * rstd * g_ff[gd + 1] + b_ff[gd + 1]);
    __syncthreads();

    // MLP1: 16 waves x 64 cols
    {
        f32x4 m1[4] = {};
        const int nb = wave * 64;
        for (int k0 = 0; k0 < 256; k0 += 32) {
            bf16x8 af = *(const bf16x8*)(fA + lr * 264 + k0 + lq * 8);
            #pragma unroll
            for (int j = 0; j < 4; j++) {
                bf16x8 bv = *(const bf16x8*)(w1_bf + (size_t)(nb + j * 16 + lr) * 256 + k0 + lq * 8);
                m1[j] = __builtin_amdgcn_mfma_f32_16x16x32_bf16(af, bv, m1[j], 0, 0, 0);
            }
        }
        #pragma unroll
        for (int j = 0; j < 4; j++) {
            int n = nb + j * 16 + lr;
            float bb = b1[n];
            if (lq < 2) {
                #pragma unroll
                for (int r = 0; r < 4; r++)
                    h1A[(lq * 4 + r) * 1032 + n] = f2bf(fmaxf(m1[j][r] + bb, 0.f));
            }
        }
    }
    __syncthreads();

    // MLP2 + residual: 16 waves x 16 cols
    {
        f32x4 m2 = {};
        const int n = wave * 16 + lr;
        for (int k0 = 0; k0 < 1024; k0 += 32) {
            bf16x8 af = *(const bf16x8*)(h1A + lr * 1032 + k0 + lq * 8);
            bf16x8 bv = *(const bf16x8*)(w2_bf + (size_t)n * 1024 + k0 + lq * 8);
            m2 = __builtin_amdgcn_mfma_f32_16x16x32_bf16(af, bv, m2, 0, 0, 0);
        }
        float bb = b2[n];
        if (lq < 2) {
            #pragma unroll
            for (int r = 0; r < 4; r++) {
                int row = lq * 4 + r;
                float val = m2[r] + bb + sbuf[row * 264 + n];
                slots[(size_t)(b * 8 + row) * 256 + n] = val;
                if (fin) out[(size_t)(b * 8 + row) * 256 + n] = val;
            }
        }
    }
}

// ---------------------------------------------------------------------------
extern "C" void kernel_launch(void* const* d_in, const int* in_sizes, int n_in,
                              void* d_out, int out_size, void* d_ws, size_t ws_size,
                              hipStream_t stream)
{
    const float* inputs = (const float*)d_in[0];
    const float* noise  = (const float*)d_in[1];
    const float* mu     = (const float*)d_in[2];
    const float* ls     = (const float*)d_in[3];
    const float* Wq     = (const float*)d_in[4];
    const float* Wk     = (const float*)d_in[5];
    const float* Wv     = (const float*)d_in[6];
    const float* wih    = (const float*)d_in[7];
    const float* whh    = (const float*)d_in[8];
    const float* bih    = (const float*)d_in[9];
    const float* bhh    = (const float*)d_in[10];
    const float* w1     = (const float*)d_in[11];
    const float* b1     = (const float*)d_in[12];
    const float* w2     = (const float*)d_in[13];
    const float* b2     = (const float*)d_in[14];
    const float* g_in   = (const float*)d_in[15];
    const float* b_in   = (const float*)d_in[16];
    const float* g_s    = (const float*)d_in[17];
    const float* b_s    = (const float*)d_in[18];
    const float* g_ff   = (const float*)d_in[19];
    const float* b_ff   = (const float*)d_in[20];
    float* out = (float*)d_out;
    char*  ws  = (char*)d_ws;

    unsigned short* x_bf   = (unsigned short*)(ws + 0);
    unsigned short* kv_bf  = (unsigned short*)(ws + 16777216);
    unsigned short* kvW_bf = (unsigned short*)(ws + 50331648);
    unsigned short* Wq_bf  = (unsigned short*)(ws + 50593792);
    unsigned short* wih_bf = (unsigned short*)(ws + 50724864);
    unsigned short* whh_bf = (unsigned short*)(ws + 51118080);
    unsigned short* w1_bf  = (unsigned short*)(ws + 51511296);
    unsigned short* w2_bf  = (unsigned short*)(ws + 52035584);
    float*          slots  = (float*)(ws + 52559872);
    float*          upart  = (float*)(ws + 52822016);   // 32*16*8*256 f32 = 4 MB
    float*          rspart = (float*)(ws + 57016320);   // 32*16*8 f32

    prep_kernel<<<12800, 256, 0, stream>>>(inputs, noise, mu, ls, Wq, Wk, Wv,
                                           wih, whh, w1, w2, g_in, b_in,
                                           x_bf, kvW_bf, Wq_bf, wih_bf, whh_bf,
                                           w1_bf, w2_bf, slots);
    kv_gemm<<<dim3(256, 4), 256, 0, stream>>>(x_bf, kvW_bf, kv_bf);
    for (int it = 0; it < 3; ++it) {
        attn_kernel<<<dim3(16, 32), 256, 0, stream>>>(slots, Wq_bf, kv_bf, g_s, b_s,
                                                      upart, rspart);
        slot_kernel<<<32, 1024, 0, stream>>>(upart, rspart, slots,
                                             wih_bf, whh_bf, w1_bf, w2_bf,
                                             bih, bhh, b1, b2, g_ff, b_ff,
                                             out, it == 2 ? 1 : 0);
    }
}

// Round 5
// 362.304 us; speedup vs baseline: 4.2834x; 1.0317x over previous
//
#include <hip/hip_runtime.h>

// ---------------------------------------------------------------------------
// SlotAttention on MI355X (gfx950). R5: 20 launches, every kernel wide.
// R4 showed slot_kernel latency-bound at 32 CUs (~32 GB/s/CU streaming);
// slot chain now ucomb/gates/mlpA/mlpB; attn dots+PV via MFMA (kills 8x
// redundant scalar k loads). GEMMs bf16 MFMA 16x16x32, rest fp32.
// Fragment layouts (learn_hip m89/m97, ref-verified):
//   A operand: A[m = lane&15][k = (lane>>4)*8 + j]  (8 contiguous bf16)
//   B operand: B[n = lane&15][k = (lane>>4)*8 + j]
//   C/D:       col(n) = lane&15, row(m) = (lane>>4)*4 + reg
// ---------------------------------------------------------------------------

typedef __attribute__((ext_vector_type(8))) __bf16 bf16x8;
typedef __attribute__((ext_vector_type(4))) float  f32x4;

static __device__ __forceinline__ unsigned short f2bf(float f) {
    unsigned int x = __float_as_uint(f);
    x = (x + 0x7fffu + ((x >> 16) & 1u)) >> 16;   // RN-even
    return (unsigned short)x;
}

// ---------------- K1: weights -> bf16, slots init, LN(inputs) -> bf16 -------
__global__ __launch_bounds__(256) void prep_kernel(
    const float* __restrict__ inputs, const float* __restrict__ noise,
    const float* __restrict__ mu, const float* __restrict__ ls,
    const float* __restrict__ Wq, const float* __restrict__ Wk,
    const float* __restrict__ Wv, const float* __restrict__ wih,
    const float* __restrict__ whh, const float* __restrict__ w1,
    const float* __restrict__ w2, const float* __restrict__ g_in,
    const float* __restrict__ b_in,
    unsigned short* __restrict__ x_bf, unsigned short* __restrict__ kvW_bf,
    unsigned short* __restrict__ Wq_bf, unsigned short* __restrict__ wih_bf,
    unsigned short* __restrict__ whh_bf, unsigned short* __restrict__ w1_bf,
    unsigned short* __restrict__ w2_bf, float* __restrict__ slots)
{
    const int blk = blockIdx.x, t = threadIdx.x;
    if (blk < 4608) {
        int g = blk * 256 + t;
        if      (g <   65536) kvW_bf[g]          = f2bf(Wk[g]);
        else if (g <  131072) kvW_bf[g]          = f2bf(Wv[g -   65536]);
        else if (g <  196608) Wq_bf[g - 131072]  = f2bf(Wq[g -  131072]);
        else if (g <  393216) wih_bf[g - 196608] = f2bf(wih[g - 196608]);
        else if (g <  589824) whh_bf[g - 393216] = f2bf(whh[g - 393216]);
        else if (g <  851968) w1_bf[g - 589824]  = f2bf(w1[g -  589824]);
        else if (g < 1114112) w2_bf[g - 851968]  = f2bf(w2[g -  851968]);
        else if (g < 1179648) {
            int i = g - 1114112, d = i & 255;
            slots[i] = mu[d] + __expf(ls[d]) * noise[i];
        }
    } else {
        const int lane = t & 63;
        float4 g4  = *(const float4*)(g_in + lane * 4);
        float4 bb4 = *(const float4*)(b_in + lane * 4);
        int row = (blk - 4608) * 4 + (t >> 6);
        float4 v = *(const float4*)(inputs + (size_t)row * 256 + lane * 4);
        float s  = v.x + v.y + v.z + v.w;
        float ss = v.x * v.x + v.y * v.y + v.z * v.z + v.w * v.w;
        #pragma unroll
        for (int o = 32; o > 0; o >>= 1) { s += __shfl_xor(s, o); ss += __shfl_xor(ss, o); }
        float mean = s * (1.f / 256.f);
        float var  = ss * (1.f / 256.f) - mean * mean;
        float rstd = rsqrtf(var + 1e-5f);
        ushort4 o4;
        o4.x = f2bf((v.x - mean) * rstd * g4.x + bb4.x);
        o4.y = f2bf((v.y - mean) * rstd * g4.y + bb4.y);
        o4.z = f2bf((v.z - mean) * rstd * g4.z + bb4.z);
        o4.w = f2bf((v.w - mean) * rstd * g4.w + bb4.w);
        *(ushort4*)(x_bf + (size_t)row * 256 + lane * 4) = o4;
    }
}

// ---------------- K2: kv = x_ln @ [Wk;Wv]^T  (bf16 out) ---------------------
__global__ __launch_bounds__(256) void kv_gemm(
    const unsigned short* __restrict__ A, const unsigned short* __restrict__ B,
    unsigned short* __restrict__ C)   // M=32768, N=512, K=256
{
    __shared__ unsigned short As[128 * 32], Bs[128 * 32];
    const int m0 = blockIdx.x * 128, n0 = blockIdx.y * 128;
    const int t = threadIdx.x, wave = t >> 6, lane = t & 63;
    const int qr = (wave >> 1) * 64, qc = (wave & 1) * 64;
    const int lr = lane & 15, lq = lane >> 4;
    f32x4 acc[4][4] = {};
    const int sr = t >> 2, sc = (t & 3) * 8;
    for (int k0 = 0; k0 < 256; k0 += 32) {
        __syncthreads();
        uint4 a0 = *(const uint4*)(A + (size_t)(m0 + sr) * 256 + k0 + sc);
        uint4 a1 = *(const uint4*)(A + (size_t)(m0 + sr + 64) * 256 + k0 + sc);
        uint4 b0 = *(const uint4*)(B + (size_t)(n0 + sr) * 256 + k0 + sc);
        uint4 b1 = *(const uint4*)(B + (size_t)(n0 + sr + 64) * 256 + k0 + sc);
        *(uint4*)(As + sr * 32 + sc) = a0;
        *(uint4*)(As + (sr + 64) * 32 + sc) = a1;
        *(uint4*)(Bs + sr * 32 + sc) = b0;
        *(uint4*)(Bs + (sr + 64) * 32 + sc) = b1;
        __syncthreads();
        bf16x8 af[4], bv[4];
        #pragma unroll
        for (int i = 0; i < 4; i++) af[i] = *(const bf16x8*)(As + (qr + i * 16 + lr) * 32 + lq * 8);
        #pragma unroll
        for (int i = 0; i < 4; i++) bv[i] = *(const bf16x8*)(Bs + (qc + i * 16 + lr) * 32 + lq * 8);
        #pragma unroll
        for (int i = 0; i < 4; i++)
            #pragma unroll
            for (int j = 0; j < 4; j++)
                acc[i][j] = __builtin_amdgcn_mfma_f32_16x16x32_bf16(af[i], bv[j], acc[i][j], 0, 0, 0);
    }
    #pragma unroll
    for (int i = 0; i < 4; i++)
        #pragma unroll
        for (int j = 0; j < 4; j++) {
            int col = n0 + qc + j * 16 + lr;
            #pragma unroll
            for (int r = 0; r < 4; r++) {
                int row = m0 + qr + i * 16 + lq * 4 + r;
                C[(size_t)row * 512 + col] = f2bf(acc[i][j][r]);
            }
        }
}

// ---------------- K3: LN_s + q = LN(slots)@Wq^T * SCALE -> bf16 -------------
// grid (4 rowgroups x 4 nslices) = 16 blocks, 256 thr.
__global__ __launch_bounds__(256) void qln_kernel(
    const float* __restrict__ slots, const unsigned short* __restrict__ Wq_bf,
    const float* __restrict__ g_s, const float* __restrict__ b_s,
    unsigned short* __restrict__ q_bf)
{
    __shared__ unsigned short sA[64 * 264];
    const int rg = blockIdx.x & 3, ns = blockIdx.x >> 2, t = threadIdx.x;
    const int lane = t & 63, wave = t >> 6, lr = lane & 15, lq = lane >> 4;
    {
        float4 g4  = *(const float4*)(g_s + lane * 4);
        float4 bb4 = *(const float4*)(b_s + lane * 4);
        for (int rr = 0; rr < 16; ++rr) {
            int rloc = wave * 16 + rr;
            float4 v = *(const float4*)(slots + (size_t)(rg * 64 + rloc) * 256 + lane * 4);
            float s  = v.x + v.y + v.z + v.w;
            float ss = v.x * v.x + v.y * v.y + v.z * v.z + v.w * v.w;
            #pragma unroll
            for (int o = 32; o > 0; o >>= 1) { s += __shfl_xor(s, o); ss += __shfl_xor(ss, o); }
            float mean = s * (1.f / 256.f);
            float var  = ss * (1.f / 256.f) - mean * mean;
            float rstd = rsqrtf(var + 1e-5f);
            ushort4 o4;
            o4.x = f2bf((v.x - mean) * rstd * g4.x + bb4.x);
            o4.y = f2bf((v.y - mean) * rstd * g4.y + bb4.y);
            o4.z = f2bf((v.z - mean) * rstd * g4.z + bb4.z);
            o4.w = f2bf((v.w - mean) * rstd * g4.w + bb4.w);
            *(ushort4*)(sA + rloc * 264 + lane * 4) = o4;
        }
    }
    __syncthreads();
    f32x4 acc[4] = {};
    for (int k0 = 0; k0 < 256; k0 += 32) {
        bf16x8 af = *(const bf16x8*)(sA + (wave * 16 + lr) * 264 + k0 + lq * 8);
        #pragma unroll
        for (int j = 0; j < 4; j++) {
            bf16x8 bv = *(const bf16x8*)(Wq_bf + (size_t)(ns * 64 + j * 16 + lr) * 256 + k0 + lq * 8);
            acc[j] = __builtin_amdgcn_mfma_f32_16x16x32_bf16(af, bv, acc[j], 0, 0, 0);
        }
    }
    #pragma unroll
    for (int j = 0; j < 4; j++) {
        int col = ns * 64 + j * 16 + lr;
        #pragma unroll
        for (int r = 0; r < 4; r++) {
            int row = rg * 64 + wave * 16 + lq * 4 + r;
            q_bf[(size_t)row * 256 + col] = f2bf(acc[j][r] * 0.0625f);  // SCALE folded
        }
    }
}

// ---------------- K4: attn — MFMA dots + softmax + MFMA PV partials ---------
// grid (16 chunks of 64 tokens, 32 batches), 256 thr.
__global__ __launch_bounds__(256) void attn_kernel(
    const unsigned short* __restrict__ q_bf, const unsigned short* __restrict__ kv_bf,
    float* __restrict__ upart, float* __restrict__ rspart)
{
    __shared__ unsigned short qA[16 * 264];  // rows 8..15 zero
    __shared__ unsigned short dA[16 * 72];   // attn bf16, rows 8..15 zero
    __shared__ float d_s[8 * 72];
    __shared__ unsigned short vT[256 * 72];  // v transposed [d][token]
    const int chunk = blockIdx.x, b = blockIdx.y, t = threadIdx.x;
    const int lane = t & 63, wave = t >> 6, lr = lane & 15, lq = lane >> 4;
    const int j0 = chunk * 64;

    {   // stage q rows (bf16)
        int i = t >> 5, c8 = (t & 31) * 8;
        *(uint4*)(qA + i * 264 + c8) = *(const uint4*)(q_bf + (size_t)(b * 8 + i) * 256 + c8);
    }
    for (int idx = t; idx < 8 * 264; idx += 256) qA[8 * 264 + idx] = 0;
    for (int idx = t; idx < 8 * 72; idx += 256) dA[8 * 72 + idx] = 0;
    #pragma unroll
    for (int p = 0; p < 8; ++p) {   // stage V transposed
        int idx = t + p * 256;
        int tok = idx >> 5, c8 = (idx & 31) * 8;
        uint4 vv = *(const uint4*)(kv_bf + ((size_t)b * 1024 + j0 + tok) * 512 + 256 + c8);
        const unsigned short* vs = (const unsigned short*)&vv;
        #pragma unroll
        for (int q = 0; q < 8; ++q) vT[(c8 + q) * 72 + tok] = vs[q];
    }
    __syncthreads();

    {   // dots: wave w -> tokens [w*16, w*16+16)
        f32x4 dd = {};
        const int tw = wave * 16;
        for (int k0 = 0; k0 < 256; k0 += 32) {
            bf16x8 aq = *(const bf16x8*)(qA + lr * 264 + k0 + lq * 8);
            bf16x8 bk = *(const bf16x8*)(kv_bf + ((size_t)b * 1024 + j0 + tw + lr) * 512 + k0 + lq * 8);
            dd = __builtin_amdgcn_mfma_f32_16x16x32_bf16(aq, bk, dd, 0, 0, 0);
        }
        if (lq < 2) {
            #pragma unroll
            for (int r = 0; r < 4; r++) d_s[(lq * 4 + r) * 72 + tw + lr] = dd[r];
        }
    }
    __syncthreads();

    if (t < 64) {   // softmax over 8 slots for token t, + EPS; row sums
        float v[8], m = -1e30f;
        #pragma unroll
        for (int ii = 0; ii < 8; ii++) { v[ii] = d_s[ii * 72 + t]; m = fmaxf(m, v[ii]); }
        float s = 0.f;
        #pragma unroll
        for (int ii = 0; ii < 8; ii++) { v[ii] = __expf(v[ii] - m); s += v[ii]; }
        float inv = 1.f / s;
        #pragma unroll
        for (int ii = 0; ii < 8; ii++) {
            float a = v[ii] * inv + 1e-8f;
            dA[ii * 72 + t] = f2bf(a);
            float rsum = a;
            #pragma unroll
            for (int o = 32; o > 0; o >>= 1) rsum += __shfl_xor(rsum, o);
            if (t == 0) rspart[((size_t)b * 16 + chunk) * 8 + ii] = rsum;
        }
    }
    __syncthreads();

    {   // PV: wave w -> d-cols [w*64, w*64+64), K = 64 tokens
        f32x4 up[4] = {};
        const int nw = wave * 64;
        #pragma unroll
        for (int k0 = 0; k0 < 64; k0 += 32) {
            bf16x8 aa = *(const bf16x8*)(dA + lr * 72 + k0 + lq * 8);
            #pragma unroll
            for (int j = 0; j < 4; j++) {
                bf16x8 bb = *(const bf16x8*)(vT + (nw + j * 16 + lr) * 72 + k0 + lq * 8);
                up[j] = __builtin_amdgcn_mfma_f32_16x16x32_bf16(aa, bb, up[j], 0, 0, 0);
            }
        }
        if (lq < 2) {
            #pragma unroll
            for (int j = 0; j < 4; j++)
                #pragma unroll
                for (int r = 0; r < 4; r++)
                    upart[(((size_t)b * 16 + chunk) * 8 + lq * 4 + r) * 256 + nw + j * 16 + lr] = up[j][r];
        }
    }
}

// ---------------- K5: combine partials -> u_bf, h_bf ------------------------
// grid 64 blocks, 256 thr (4 rows/block).
__global__ __launch_bounds__(256) void ucomb_kernel(
    const float* __restrict__ upart, const float* __restrict__ rspart,
    const float* __restrict__ slots,
    unsigned short* __restrict__ u_bf, unsigned short* __restrict__ h_bf)
{
    const int t = threadIdx.x, lane = t & 63;
    const int row = blockIdx.x * 4 + (t >> 6);
    const int b = row >> 3, i = row & 7;
    float rs = 0.f;
    #pragma unroll
    for (int c = 0; c < 16; c++) rs += rspart[((size_t)b * 16 + c) * 8 + i];
    float4 acc = {0.f, 0.f, 0.f, 0.f};
    #pragma unroll
    for (int c = 0; c < 16; c++) {
        float4 u = *(const float4*)(upart + (((size_t)b * 16 + c) * 8 + i) * 256 + lane * 4);
        acc.x += u.x; acc.y += u.y; acc.z += u.z; acc.w += u.w;
    }
    float inv = 1.f / rs;
    ushort4 o4;
    o4.x = f2bf(acc.x * inv); o4.y = f2bf(acc.y * inv);
    o4.z = f2bf(acc.z * inv); o4.w = f2bf(acc.w * inv);
    *(ushort4*)(u_bf + (size_t)row * 256 + lane * 4) = o4;
    float4 h = *(const float4*)(slots + (size_t)row * 256 + lane * 4);
    ushort4 h4;
    h4.x = f2bf(h.x); h4.y = f2bf(h.y); h4.z = f2bf(h.z); h4.w = f2bf(h.w);
    *(ushort4*)(h_bf + (size_t)row * 256 + lane * 4) = h4;
}

// ---------------- K6: gates GEMM + GRU -> s_pre, lnpart ---------------------
// grid (4 rowgroups x 8 e-slices of 32) = 32 blocks, 256 thr.
__global__ __launch_bounds__(256) void gates_kernel(
    const unsigned short* __restrict__ u_bf, const unsigned short* __restrict__ h_bf,
    const unsigned short* __restrict__ wih_bf, const unsigned short* __restrict__ whh_bf,
    const float* __restrict__ bih, const float* __restrict__ bhh,
    const float* __restrict__ slots,
    float* __restrict__ s_pre, float* __restrict__ lnpart)
{
    __shared__ unsigned short uA[64 * 264], hA[64 * 264];
    const int rgrp = blockIdx.x & 3, es = blockIdx.x >> 2, t = threadIdx.x;
    const int lane = t & 63, wave = t >> 6, lr = lane & 15, lq = lane >> 4;
    const int e0 = es * 32;

    for (int idx = t; idx < 2048; idx += 256) {
        int rloc = idx >> 5, c8 = (idx & 31) * 8;
        *(uint4*)(uA + rloc * 264 + c8) = *(const uint4*)(u_bf + (size_t)(rgrp * 64 + rloc) * 256 + c8);
        *(uint4*)(hA + rloc * 264 + c8) = *(const uint4*)(h_bf + (size_t)(rgrp * 64 + rloc) * 256 + c8);
    }
    __syncthreads();

    f32x4 aI[3][2] = {}, aH[3][2] = {};
    for (int k0 = 0; k0 < 256; k0 += 32) {
        bf16x8 au = *(const bf16x8*)(uA + (wave * 16 + lr) * 264 + k0 + lq * 8);
        bf16x8 ah = *(const bf16x8*)(hA + (wave * 16 + lr) * 264 + k0 + lq * 8);
        #pragma unroll
        for (int g = 0; g < 3; g++)
            #pragma unroll
            for (int s = 0; s < 2; s++) {
                int wr = g * 256 + e0 + s * 16 + lr;
                bf16x8 bi_ = *(const bf16x8*)(wih_bf + (size_t)wr * 256 + k0 + lq * 8);
                bf16x8 bh_ = *(const bf16x8*)(whh_bf + (size_t)wr * 256 + k0 + lq * 8);
                aI[g][s] = __builtin_amdgcn_mfma_f32_16x16x32_bf16(au, bi_, aI[g][s], 0, 0, 0);
                aH[g][s] = __builtin_amdgcn_mfma_f32_16x16x32_bf16(ah, bh_, aH[g][s], 0, 0, 0);
            }
    }
    #pragma unroll
    for (int r = 0; r < 4; r++) {
        int row = rgrp * 64 + wave * 16 + lq * 4 + r;
        float ps = 0.f, pq = 0.f;
        #pragma unroll
        for (int s = 0; s < 2; s++) {
            int e = e0 + s * 16 + lr;
            float ir = aI[0][s][r] + bih[e];
            float iz = aI[1][s][r] + bih[256 + e];
            float in_= aI[2][s][r] + bih[512 + e];
            float hr = aH[0][s][r] + bhh[e];
            float hz = aH[1][s][r] + bhh[256 + e];
            float hn = aH[2][s][r] + bhh[512 + e];
            float rG = 1.f / (1.f + __expf(-(ir + hr)));
            float z  = 1.f / (1.f + __expf(-(iz + hz)));
            float a = in_ + rG * hn;
            a = fminf(fmaxf(a, -15.f), 15.f);
            float ee = __expf(2.f * a);
            float nn = (ee - 1.f) / (ee + 1.f);
            float h = slots[(size_t)row * 256 + e];
            float sn = (1.f - z) * nn + z * h;
            s_pre[(size_t)row * 256 + e] = sn;
            ps += sn; pq += sn * sn;
        }
        #pragma unroll
        for (int o = 8; o > 0; o >>= 1) { ps += __shfl_xor(ps, o); pq += __shfl_xor(pq, o); }
        if (lr == 0) {
            lnpart[(size_t)row * 16 + es * 2]     = ps;
            lnpart[(size_t)row * 16 + es * 2 + 1] = pq;
        }
    }
}

// ---------------- K7: LN_ff + MLP1 (relu) -> h1_bf --------------------------
// grid (4 rowgroups x 8 n-slices of 128) = 32 blocks, 256 thr.
__global__ __launch_bounds__(256) void mlp1_kernel(
    const float* __restrict__ s_pre, const float* __restrict__ lnpart,
    const unsigned short* __restrict__ w1_bf, const float* __restrict__ b1,
    const float* __restrict__ g_ff, const float* __restrict__ b_ff,
    unsigned short* __restrict__ h1_bf)
{
    __shared__ unsigned short fA[64 * 264];
    __shared__ float meanS[64], rstdS[64];
    const int rgrp = blockIdx.x & 3, ns = blockIdx.x >> 2, t = threadIdx.x;
    const int lane = t & 63, wave = t >> 6, lr = lane & 15, lq = lane >> 4;
    const int n0 = ns * 128;

    if (t < 64) {
        int row = rgrp * 64 + t;
        float S = 0.f, SS = 0.f;
        #pragma unroll
        for (int j = 0; j < 8; j++) {
            S  += lnpart[(size_t)row * 16 + j * 2];
            SS += lnpart[(size_t)row * 16 + j * 2 + 1];
        }
        float mean = S * (1.f / 256.f);
        float var  = SS * (1.f / 256.f) - mean * mean;
        meanS[t] = mean;
        rstdS[t] = rsqrtf(var + 1e-5f);
    }
    __syncthreads();
    for (int idx = t; idx < 2048; idx += 256) {
        int rloc = idx >> 5, c8 = (idx & 31) * 8;
        float mean = meanS[rloc], rstd = rstdS[rloc];
        const float* sp = s_pre + (size_t)(rgrp * 64 + rloc) * 256 + c8;
        float4 v0 = *(const float4*)sp, v1 = *(const float4*)(sp + 4);
        float4 g0 = *(const float4*)(g_ff + c8), g1 = *(const float4*)(g_ff + c8 + 4);
        float4 bb0 = *(const float4*)(b_ff + c8), bb1 = *(const float4*)(b_ff + c8 + 4);
        ushort4 o0, o1;
        o0.x = f2bf((v0.x - mean) * rstd * g0.x + bb0.x);
        o0.y = f2bf((v0.y - mean) * rstd * g0.y + bb0.y);
        o0.z = f2bf((v0.z - mean) * rstd * g0.z + bb0.z);
        o0.w = f2bf((v0.w - mean) * rstd * g0.w + bb0.w);
        o1.x = f2bf((v1.x - mean) * rstd * g1.x + bb1.x);
        o1.y = f2bf((v1.y - mean) * rstd * g1.y + bb1.y);
        o1.z = f2bf((v1.z - mean) * rstd * g1.z + bb1.z);
        o1.w = f2bf((v1.w - mean) * rstd * g1.w + bb1.w);
        *(ushort4*)(fA + rloc * 264 + c8)     = o0;
        *(ushort4*)(fA + rloc * 264 + c8 + 4) = o1;
    }
    __syncthreads();

    f32x4 acc[8] = {};
    for (int k0 = 0; k0 < 256; k0 += 32) {
        bf16x8 af = *(const bf16x8*)(fA + (wave * 16 + lr) * 264 + k0 + lq * 8);
        #pragma unroll
        for (int j = 0; j < 8; j++) {
            bf16x8 bv = *(const bf16x8*)(w1_bf + (size_t)(n0 + j * 16 + lr) * 256 + k0 + lq * 8);
            acc[j] = __builtin_amdgcn_mfma_f32_16x16x32_bf16(af, bv, acc[j], 0, 0, 0);
        }
    }
    #pragma unroll
    for (int j = 0; j < 8; j++) {
        int col = n0 + j * 16 + lr;
        float bb = b1[col];
        #pragma unroll
        for (int r = 0; r < 4; r++) {
            int row = rgrp * 64 + wave * 16 + lq * 4 + r;
            h1_bf[(size_t)row * 1024 + col] = f2bf(fmaxf(acc[j][r] + bb, 0.f));
        }
    }
}

// ---------------- K8: MLP2 + residual -> slots (+out) -----------------------
// grid (4 rowgroups x 8 n-slices of 32) = 32 blocks, 256 thr. K=1024 from global.
__global__ __launch_bounds__(256) void mlp2_kernel(
    const unsigned short* __restrict__ h1_bf, const unsigned short* __restrict__ w2_bf,
    const float* __restrict__ b2, const float* __restrict__ s_pre,
    float* __restrict__ slots, float* __restrict__ out, int fin)
{
    const int rgrp = blockIdx.x & 3, ns = blockIdx.x >> 2, t = threadIdx.x;
    const int lane = t & 63, wave = t >> 6, lr = lane & 15, lq = lane >> 4;
    const int n0 = ns * 32;
    f32x4 acc[2] = {};
    for (int k0 = 0; k0 < 1024; k0 += 32) {
        bf16x8 af = *(const bf16x8*)(h1_bf + (size_t)(rgrp * 64 + wave * 16 + lr) * 1024 + k0 + lq * 8);
        #pragma unroll
        for (int j = 0; j < 2; j++) {
            bf16x8 bv = *(const bf16x8*)(w2_bf + (size_t)(n0 + j * 16 + lr) * 1024 + k0 + lq * 8);
            acc[j] = __builtin_amdgcn_mfma_f32_16x16x32_bf16(af, bv, acc[j], 0, 0, 0);
        }
    }
    #pragma unroll
    for (int j = 0; j < 2; j++) {
        int e = n0 + j * 16 + lr;
        float bb = b2[e];
        #pragma unroll
        for (int r = 0; r < 4; r++) {
            int row = rgrp * 64 + wave * 16 + lq * 4 + r;
            float val = acc[j][r] + bb + s_pre[(size_t)row * 256 + e];
            slots[(size_t)row * 256 + e] = val;
            if (fin) out[(size_t)row * 256 + e] = val;
        }
    }
}

// ---------------------------------------------------------------------------
extern "C" void kernel_launch(void* const* d_in, const int* in_sizes, int n_in,
                              void* d_out, int out_size, void* d_ws, size_t ws_size,
                              hipStream_t stream)
{
    const float* inputs = (const float*)d_in[0];
    const float* noise  = (const float*)d_in[1];
    const float* mu     = (const float*)d_in[2];
    const float* ls     = (const float*)d_in[3];
    const float* Wq     = (const float*)d_in[4];
    const float* Wk     = (const float*)d_in[5];
    const float* Wv     = (const float*)d_in[6];
    const float* wih    = (const float*)d_in[7];
    const float* whh    = (const float*)d_in[8];
    const float* bih    = (const float*)d_in[9];
    const float* bhh    = (const float*)d_in[10];
    const float* w1     = (const float*)d_in[11];
    const float* b1     = (const float*)d_in[12];
    const float* w2     = (const float*)d_in[13];
    const float* b2     = (const float*)d_in[14];
    const float* g_in   = (const float*)d_in[15];
    const float* b_in   = (const float*)d_in[16];
    const float* g_s    = (const float*)d_in[17];
    const float* b_s    = (const float*)d_in[18];
    const float* g_ff   = (const float*)d_in[19];
    const float* b_ff   = (const float*)d_in[20];
    float* out = (float*)d_out;
    char*  ws  = (char*)d_ws;

    unsigned short* x_bf   = (unsigned short*)(ws + 0);
    unsigned short* kv_bf  = (unsigned short*)(ws + 16777216);
    unsigned short* kvW_bf = (unsigned short*)(ws + 50331648);
    unsigned short* Wq_bf  = (unsigned short*)(ws + 50593792);
    unsigned short* wih_bf = (unsigned short*)(ws + 50724864);
    unsigned short* whh_bf = (unsigned short*)(ws + 51118080);
    unsigned short* w1_bf  = (unsigned short*)(ws + 51511296);
    unsigned short* w2_bf  = (unsigned short*)(ws + 52035584);
    float*          slots  = (float*)(ws + 52559872);
    float*          upart  = (float*)(ws + 52822016);   // 4 MB
    float*          rspart = (float*)(ws + 57016320);   // 16 KB
    unsigned short* q_bf   = (unsigned short*)(ws + 57032704);
    unsigned short* u_bf   = (unsigned short*)(ws + 57163776);
    unsigned short* h_bf   = (unsigned short*)(ws + 57294848);
    float*          s_pre  = (float*)(ws + 57425920);
    float*          lnpart = (float*)(ws + 57688064);
    unsigned short* h1_bf  = (unsigned short*)(ws + 57704448);

    prep_kernel<<<12800, 256, 0, stream>>>(inputs, noise, mu, ls, Wq, Wk, Wv,
                                           wih, whh, w1, w2, g_in, b_in,
                                           x_bf, kvW_bf, Wq_bf, wih_bf, whh_bf,
                                           w1_bf, w2_bf, slots);
    kv_gemm<<<dim3(256, 4), 256, 0, stream>>>(x_bf, kvW_bf, kv_bf);
    for (int it = 0; it < 3; ++it) {
        qln_kernel<<<16, 256, 0, stream>>>(slots, Wq_bf, g_s, b_s, q_bf);
        attn_kernel<<<dim3(16, 32), 256, 0, stream>>>(q_bf, kv_bf, upart, rspart);
        ucomb_kernel<<<64, 256, 0, stream>>>(upart, rspart, slots, u_bf, h_bf);
        gates_kernel<<<32, 256, 0, stream>>>(u_bf, h_bf, wih_bf, whh_bf, bih, bhh,
                                             slots, s_pre, lnpart);
        mlp1_kernel<<<32, 256, 0, stream>>>(s_pre, lnpart, w1_bf, b1, g_ff, b_ff, h1_bf);
        mlp2_kernel<<<32, 256, 0, stream>>>(h1_bf, w2_bf, b2, s_pre, slots, out,
                                            it == 2 ? 1 : 0);
    }
}